// Round 4
// baseline (501.032 us; speedup 1.0000x reference)
//
#include <hip/hip_runtime.h>
#include <cstdint>
#include <cstddef>

// ---------------------------------------------------------------------------
// Problem constants (LEVEL=16, LENGTH=64, TOPK=2, SIZE=512, BATCH=32)
// Inputs f32, outputs f32. Uniform absmax threshold 2.06 across outputs =>
// precision only matters for ORDERING near-ties (topk_n_idx needs |dn|<=2).
// Strategy: single-pass f16 MFMA for scores (err sigma ~0.016) + exact f32
// refinement of positions whose cheap top-2/3 gaps are < DELTA=0.25 (~15 sigma).
//
// r3 bug (fixed here): chart rows = 57,856, elems = 57,856*512 = 29,622,272
// (NOT 29,605,888). T16 was sized 32 KB short -> K1's last m-tile clobbered
// MAT16 while other blocks read it -> f16-saturated T' -> topk_s ~2800.
// ---------------------------------------------------------------------------
#define B_DIM   32
#define L_DIM   48
#define NCELLS  904
#define SZ      512
#define NEGF    (-1e8f)
#define DELTA   0.25f

#define CH_ELEMS   29622272u        // 2*32*904*512
#define CH_BYTES_F16 59244544u      // CH_ELEMS * 2

// d_out layout (f32), outputs concatenated flat in return order
#define OFF_S   1572864
#define OFF_N   1575936
#define OFF_L   1579008
#define OFF_R   1582080

typedef _Float16  f16x8 __attribute__((ext_vector_type(8)));
typedef float     f32x4 __attribute__((ext_vector_type(4)));

static __device__ __forceinline__ uint16_t f2bf(float f) {
    uint32_t u = __builtin_bit_cast(uint32_t, f);
    u += 0x7fffu + ((u >> 16) & 1u);
    return (uint16_t)(u >> 16);
}

#define GLD16(gp, lp) __builtin_amdgcn_global_load_lds(                        \
        (__attribute__((address_space(1))) void*)(gp),                         \
        (__attribute__((address_space(3))) void*)(lp), 16, 0, 0)

static __device__ __forceinline__ int level_off(int n) {
    return n * 64 - (n * (n - 1)) / 2;
}

// ---------------------------------------------------------------------------
// P0: chart_hf16 = f16(16*chart_h); matf16 = f16(64*mat)
// grid 14464 * 256 threads * 8 elems = 29,622,272 exactly.
// ---------------------------------------------------------------------------
__global__ __launch_bounds__(256)
void prep(const float* __restrict__ ch, const float* __restrict__ mat,
          _Float16* __restrict__ ch16, _Float16* __restrict__ mat16)
{
    const size_t i = ((size_t)blockIdx.x * 256 + threadIdx.x) * 8;
    const float4 a = *(const float4*)(ch + i);
    const float4 b = *(const float4*)(ch + i + 4);
    f16x8 v;
    v[0]=(_Float16)(a.x*16.f); v[1]=(_Float16)(a.y*16.f);
    v[2]=(_Float16)(a.z*16.f); v[3]=(_Float16)(a.w*16.f);
    v[4]=(_Float16)(b.x*16.f); v[5]=(_Float16)(b.y*16.f);
    v[6]=(_Float16)(b.z*16.f); v[7]=(_Float16)(b.w*16.f);
    *(f16x8*)(ch16 + i) = v;
    if (blockIdx.x < 128) {
        const size_t j = ((size_t)blockIdx.x * 256 + threadIdx.x) * 8;
        const float4 c = *(const float4*)(mat + j);
        const float4 d = *(const float4*)(mat + j + 4);
        f16x8 w;
        w[0]=(_Float16)(c.x*64.f); w[1]=(_Float16)(c.y*64.f);
        w[2]=(_Float16)(c.z*64.f); w[3]=(_Float16)(c.w*64.f);
        w[4]=(_Float16)(d.x*64.f); w[5]=(_Float16)(d.y*64.f);
        w[6]=(_Float16)(d.z*64.f); w[7]=(_Float16)(d.w*64.f);
        *(f16x8*)(mat16 + j) = w;
    }
}

// ---------------------------------------------------------------------------
// K1: T'[m,e] = sum_d A16[m,d]*B16[e,d]  (f16 in, f16 out, x1024 scaled)
// m97 structure: 128x128 tile, BK=64, grid x = n-tiles (fastest) for A reuse.
// ---------------------------------------------------------------------------
__global__ __launch_bounds__(256, 2)
void gemm_f16(const _Float16* __restrict__ A,
              const _Float16* __restrict__ Bm,
              _Float16* __restrict__ C,
              int M, int Nn, int Kk)
{
    __shared__ _Float16 As[128 * 64];
    __shared__ _Float16 Bs[128 * 64];

    const int tid  = threadIdx.x;
    const int wave = tid >> 6, lane = tid & 63;
    const int m0 = blockIdx.y * 128, n0 = blockIdx.x * 128;
    const int wm = (wave & 1) * 64, wn = (wave >> 1) * 64;
    const int col_l = lane & 15, quad = lane >> 4;
    const int lrow = lane >> 3;
    const int lcol = (lane & 7) * 8;

    f32x4 acc[4][4];
#pragma unroll
    for (int i = 0; i < 4; ++i)
#pragma unroll
        for (int j = 0; j < 4; ++j) acc[i][j] = (f32x4){0.f, 0.f, 0.f, 0.f};

    for (int k0 = 0; k0 < Kk; k0 += 64) {
        __syncthreads();
#pragma unroll
        for (int i = 0; i < 4; ++i) {
            const int q = wave * 4 + i;
            const int r = q * 8 + lrow;
            GLD16(A  + (size_t)(m0 + r) * Kk + k0 + lcol, (char*)As + q * 1024);
            GLD16(Bm + (size_t)(n0 + r) * Kk + k0 + lcol, (char*)Bs + q * 1024);
        }
        __syncthreads();
#pragma unroll
        for (int kk = 0; kk < 64; kk += 32) {
            f16x8 af[4], bfr[4];
#pragma unroll
            for (int mi = 0; mi < 4; ++mi)
                af[mi] = *(const f16x8*)&As[(wm + mi * 16 + col_l) * 64 + kk + quad * 8];
#pragma unroll
            for (int ni = 0; ni < 4; ++ni)
                bfr[ni] = *(const f16x8*)&Bs[(wn + ni * 16 + col_l) * 64 + kk + quad * 8];
#pragma unroll
            for (int mi = 0; mi < 4; ++mi)
#pragma unroll
                for (int ni = 0; ni < 4; ++ni)
                    acc[mi][ni] = __builtin_amdgcn_mfma_f32_16x16x32_f16(
                        af[mi], bfr[ni], acc[mi][ni], 0, 0, 0);
        }
    }

#pragma unroll
    for (int ni = 0; ni < 4; ++ni) {
        const int ncol = n0 + wn + ni * 16 + col_l;
#pragma unroll
        for (int mi = 0; mi < 4; ++mi) {
            const int mrow = m0 + wm + mi * 16 + quad * 4;
#pragma unroll
            for (int r = 0; r < 4; ++r)
                C[(size_t)(mrow + r) * Nn + ncol] = (_Float16)acc[mi][ni][r];
        }
    }
}

// ---------------------------------------------------------------------------
// shared epilogue: write the 8 scalar outputs + gather X rows
// ---------------------------------------------------------------------------
static __device__ __forceinline__ void emit_outputs(
    int row, int i1, int i2, float v1, float v2, float* out)
{
    out[OFF_S + row * 2 + 0] = v1;
    out[OFF_S + row * 2 + 1] = v2;
    out[OFF_N + row * 2 + 0] = (float)(i1 >> 2);
    out[OFF_N + row * 2 + 1] = (float)(i2 >> 2);
    out[OFF_L + row * 2 + 0] = (float)((i1 >> 1) & 1);
    out[OFF_L + row * 2 + 1] = (float)((i2 >> 1) & 1);
    out[OFF_R + row * 2 + 0] = (float)(i1 & 1);
    out[OFF_R + row * 2 + 1] = (float)(i2 & 1);
}

static __device__ __forceinline__ void gather_x(
    int row, int pos, int b, const int* top_z,
    const float* __restrict__ chart_h, uint16_t* __restrict__ X, int tid)
{
#pragma unroll
    for (int kq = 0; kq < 2; ++kq) {
        const int z = top_z[kq];
        const int n = z >> 2, lk = (z >> 1) & 1, rk = z & 1;
        const int lcell = level_off(n) + pos;
        const int rcell = level_off(15 - n) + pos + n + 1;
        const float* srcl = chart_h + ((size_t)(lk * B_DIM + b) * NCELLS + lcell) * SZ;
        const float* srcr = chart_h + ((size_t)(rk * B_DIM + b) * NCELLS + rcell) * SZ;
        uint16_t* dst = X + ((size_t)row * 2 + kq) * 1024;
        const int e = tid * 2;
        const float2 a = *(const float2*)(srcl + e);
        const float2 c = *(const float2*)(srcr + e);
        *(uint32_t*)(dst + e)       = (uint32_t)f2bf(a.x) | ((uint32_t)f2bf(a.y) << 16);
        *(uint32_t*)(dst + 512 + e) = (uint32_t)f2bf(c.x) | ((uint32_t)f2bf(c.y) << 16);
    }
}

// ---------------------------------------------------------------------------
// K2: cheap scores (f16 dot, f32 accum), top-3, flag near-ties; for clean
// positions emit outputs + gather X. Stores all 64 cheap scores for refine.
// ---------------------------------------------------------------------------
__global__ __launch_bounds__(256)
void score_topk(const _Float16* __restrict__ ch16,   // x16
                const _Float16* __restrict__ T16,    // x1024
                const float* __restrict__ chart_s,
                const float* __restrict__ chart_h,   // f32 (X gather)
                float* __restrict__ s_all,           // [1536][64]
                int* __restrict__ flags,             // [1536]
                uint16_t* __restrict__ X,
                float* __restrict__ out)
{
    const int b   = blockIdx.x / L_DIM;
    const int pos = blockIdx.x % L_DIM;
    const int row = blockIdx.x;
    const int wave = threadIdx.x >> 6, lane = threadIdx.x & 63;

    __shared__ float s_sh[64];
    __shared__ int top_z[2];
    __shared__ int flag_sh;

#pragma unroll
    for (int ni = 0; ni < 4; ++ni) {
        const int n = wave * 4 + ni;
        const int lcell = level_off(n) + pos;
        const int rcell = level_off(15 - n) + pos + n + 1;

        const f16x8 l0 = *(const f16x8*)(ch16 + ((size_t)(0 * B_DIM + b) * NCELLS + lcell) * SZ + lane * 8);
        const f16x8 l1 = *(const f16x8*)(ch16 + ((size_t)(1 * B_DIM + b) * NCELLS + lcell) * SZ + lane * 8);
        const f16x8 t0 = *(const f16x8*)(T16 + ((size_t)(0 * B_DIM + b) * NCELLS + rcell) * SZ + lane * 8);
        const f16x8 t1 = *(const f16x8*)(T16 + ((size_t)(1 * B_DIM + b) * NCELLS + rcell) * SZ + lane * 8);

        float d00 = 0.f, d01 = 0.f, d10 = 0.f, d11 = 0.f;
#pragma unroll
        for (int j = 0; j < 8; ++j) {
            const float a0 = (float)l0[j], a1 = (float)l1[j];
            const float c0 = (float)t0[j], c1 = (float)t1[j];
            d00 += a0 * c0; d01 += a0 * c1;
            d10 += a1 * c0; d11 += a1 * c1;
        }
#pragma unroll
        for (int o = 32; o > 0; o >>= 1) {
            d00 += __shfl_down(d00, o);
            d01 += __shfl_down(d01, o);
            d10 += __shfl_down(d10, o);
            d11 += __shfl_down(d11, o);
        }
        if (lane == 0) {
            const float ls0 = chart_s[(size_t)(0 * B_DIM + b) * NCELLS + lcell];
            const float ls1 = chart_s[(size_t)(1 * B_DIM + b) * NCELLS + lcell];
            const float rs0 = chart_s[(size_t)(0 * B_DIM + b) * NCELLS + rcell];
            const float rs1 = chart_s[(size_t)(1 * B_DIM + b) * NCELLS + rcell];
            const float inv = 1.0f / 16384.0f;       // undo 16 * 1024
            s_sh[n * 4 + 0] = d00 * inv + ls0 + rs0;
            s_sh[n * 4 + 1] = d01 * inv + ls0 + rs1;
            s_sh[n * 4 + 2] = d10 * inv + ls1 + rs0;
            s_sh[n * 4 + 3] = d11 * inv + ls1 + rs1;
        }
    }
    __syncthreads();

    if (threadIdx.x < 64) {
        float v = s_sh[lane];
        if (lane == 2 || lane == 3) v = NEGF;        // penalty mask
        s_all[(size_t)row * 64 + lane] = v;          // post-penalty, for refine
        float v1 = v; int i1 = lane;
#pragma unroll
        for (int o = 32; o > 0; o >>= 1) {
            float ov = __shfl_down(v1, o);
            int   oi = __shfl_down(i1, o);
            if (ov > v1 || (ov == v1 && oi < i1)) { v1 = ov; i1 = oi; }
        }
        v1 = __shfl(v1, 0); i1 = __shfl(i1, 0);
        float v2 = (lane == i1) ? -3.4e38f : v; int i2 = lane;
#pragma unroll
        for (int o = 32; o > 0; o >>= 1) {
            float ov = __shfl_down(v2, o);
            int   oi = __shfl_down(i2, o);
            if (ov > v2 || (ov == v2 && oi < i2)) { v2 = ov; i2 = oi; }
        }
        v2 = __shfl(v2, 0); i2 = __shfl(i2, 0);
        float v3 = (lane == i1 || lane == i2) ? -3.4e38f : v;
#pragma unroll
        for (int o = 32; o > 0; o >>= 1) {
            const float ov = __shfl_down(v3, o);
            if (ov > v3) v3 = ov;
        }
        if (lane == 0) {
            const int f = (v1 - v2 < DELTA) || (v2 - v3 < DELTA);
            flags[row] = f;
            flag_sh = f;
            top_z[0] = i1; top_z[1] = i2;
            if (!f) emit_outputs(row, i1, i2, v1, v2, out);
        }
    }
    __syncthreads();

    if (!flag_sh)
        gather_x(row, pos, b, top_z, chart_h, X, threadIdx.x);
}

// ---------------------------------------------------------------------------
// K3: exact f32 refinement of flagged positions. Candidates = combos whose
// cheap score >= cheap_top2 - DELTA (provably contains the true top-2 when
// DELTA > 2*|cheap err|). Exact: s = lh . (mat @ rh) + ls + rs.
// ---------------------------------------------------------------------------
__global__ __launch_bounds__(256)
void refine(const float* __restrict__ chart_h,
            const float* __restrict__ chart_s,
            const float* __restrict__ mat,
            const float* __restrict__ s_all,
            const int* __restrict__ flags,
            uint16_t* __restrict__ X,
            float* __restrict__ out)
{
    const int row = blockIdx.x;
    if (flags[row] == 0) return;
    const int b = row / L_DIM, pos = row % L_DIM;
    const int t = threadIdx.x;

    __shared__ float sc[64];
    __shared__ int   cz[64];
    __shared__ int   ncand_sh;
    __shared__ float rhld[512];
    __shared__ float red[256];
    __shared__ float exval[64];
    __shared__ int   top_z[2];

    if (t < 64) sc[t] = s_all[(size_t)row * 64 + t];
    __syncthreads();
    if (t == 0) {
        float v1 = -3.4e38f; int i1 = -1;
        for (int z = 0; z < 64; ++z) if (sc[z] > v1) { v1 = sc[z]; i1 = z; }
        float v2 = -3.4e38f;
        for (int z = 0; z < 64; ++z) if (z != i1 && sc[z] > v2) v2 = sc[z];
        int nc = 0;
        for (int z = 0; z < 64; ++z) if (sc[z] >= v2 - DELTA) cz[nc++] = z;
        ncand_sh = nc;
    }
    __syncthreads();
    const int nc = ncand_sh;

    for (int c = 0; c < nc; ++c) {
        const int z = cz[c];
        const int n = z >> 2, lk = (z >> 1) & 1, rk = z & 1;
        const int lcell = level_off(n) + pos;
        const int rcell = level_off(15 - n) + pos + n + 1;
        const float* rhp = chart_h + ((size_t)(rk * B_DIM + b) * NCELLS + rcell) * SZ;
        rhld[t] = rhp[t];
        rhld[t + 256] = rhp[t + 256];
        __syncthreads();

        const float* lhp = chart_h + ((size_t)(lk * B_DIM + b) * NCELLS + lcell) * SZ;
        float part = 0.f;
#pragma unroll
        for (int half = 0; half < 2; ++half) {
            const int e = t + half * 256;
            const float4* mr = (const float4*)(mat + (size_t)e * 512);
            float a0 = 0.f, a1 = 0.f, a2 = 0.f, a3 = 0.f;
            for (int q = 0; q < 128; q += 4) {
                const float4 m0 = mr[q], m1 = mr[q + 1], m2 = mr[q + 2], m3 = mr[q + 3];
                const int eo = q * 4;
                a0 += m0.x*rhld[eo+ 0] + m0.y*rhld[eo+ 1] + m0.z*rhld[eo+ 2] + m0.w*rhld[eo+ 3];
                a1 += m1.x*rhld[eo+ 4] + m1.y*rhld[eo+ 5] + m1.z*rhld[eo+ 6] + m1.w*rhld[eo+ 7];
                a2 += m2.x*rhld[eo+ 8] + m2.y*rhld[eo+ 9] + m2.z*rhld[eo+10] + m2.w*rhld[eo+11];
                a3 += m3.x*rhld[eo+12] + m3.y*rhld[eo+13] + m3.z*rhld[eo+14] + m3.w*rhld[eo+15];
            }
            part += lhp[e] * (a0 + a1 + a2 + a3);
        }
        red[t] = part;
        __syncthreads();
        if (t < 128) red[t] += red[t + 128];
        __syncthreads();
        if (t < 64) {
            float v = red[t] + red[t + 64];
#pragma unroll
            for (int o = 32; o > 0; o >>= 1) v += __shfl_down(v, o);
            if (t == 0) {
                const float ls = chart_s[(size_t)(lk * B_DIM + b) * NCELLS + lcell];
                const float rs = chart_s[(size_t)(rk * B_DIM + b) * NCELLS + rcell];
                exval[c] = v + ls + rs;
            }
        }
        __syncthreads();
    }

    if (t == 0) {
        float v1 = -3.4e38f; int c1 = -1;
        for (int c = 0; c < nc; ++c) if (exval[c] > v1) { v1 = exval[c]; c1 = c; }
        float v2 = -3.4e38f; int c2 = -1;
        for (int c = 0; c < nc; ++c) if (c != c1 && exval[c] > v2) { v2 = exval[c]; c2 = c; }
        const int i1 = cz[c1], i2 = cz[c2];
        top_z[0] = i1; top_z[1] = i2;
        emit_outputs(row, i1, i2, v1, v2, out);
    }
    __syncthreads();
    gather_x(row, pos, b, top_z, chart_h, X, t);
}

// ---------------------------------------------------------------------------
// transpose_wc: WcT[o][i] = bf16(Wc[i][o])
// ---------------------------------------------------------------------------
__global__ __launch_bounds__(256)
void transpose_wc(const float* __restrict__ Wc, uint16_t* __restrict__ WcT)
{
    __shared__ float tbuf[64][65];
    const int i0 = blockIdx.x * 64;
    const int o0 = blockIdx.y * 64;
    const int c = threadIdx.x & 63, r4 = threadIdx.x >> 6;
    for (int rr = r4; rr < 64; rr += 4)
        tbuf[rr][c] = Wc[(size_t)(i0 + rr) * 512 + o0 + c];
    __syncthreads();
    for (int rr = r4; rr < 64; rr += 4)
        WcT[(size_t)(o0 + rr) * 1024 + i0 + c] = f2bf(tbuf[c][rr]);
}

// ---------------------------------------------------------------------------
// K4: H = tanh(X @ WcT^T + bc)  (bf16 in, f32 out)
// ---------------------------------------------------------------------------
typedef __bf16 bf16x8 __attribute__((ext_vector_type(8)));

__global__ __launch_bounds__(256, 2)
void gemm_compose(const uint16_t* __restrict__ A,
                  const uint16_t* __restrict__ Bm,
                  const float* __restrict__ bias,
                  float* __restrict__ C,
                  int M, int Nn, int Kk)
{
    __shared__ uint16_t As[128 * 64];
    __shared__ uint16_t Bs[128 * 64];

    const int tid  = threadIdx.x;
    const int wave = tid >> 6, lane = tid & 63;
    const int m0 = blockIdx.x * 128, n0 = blockIdx.y * 128;
    const int wm = (wave & 1) * 64, wn = (wave >> 1) * 64;
    const int col_l = lane & 15, quad = lane >> 4;
    const int lrow = lane >> 3;
    const int lcol = (lane & 7) * 8;

    f32x4 acc[4][4];
#pragma unroll
    for (int i = 0; i < 4; ++i)
#pragma unroll
        for (int j = 0; j < 4; ++j) acc[i][j] = (f32x4){0.f, 0.f, 0.f, 0.f};

    for (int k0 = 0; k0 < Kk; k0 += 64) {
        __syncthreads();
#pragma unroll
        for (int i = 0; i < 4; ++i) {
            const int q = wave * 4 + i;
            const int r = q * 8 + lrow;
            GLD16(A  + (size_t)(m0 + r) * Kk + k0 + lcol, (char*)As + q * 1024);
            GLD16(Bm + (size_t)(n0 + r) * Kk + k0 + lcol, (char*)Bs + q * 1024);
        }
        __syncthreads();
#pragma unroll
        for (int kk = 0; kk < 64; kk += 32) {
            bf16x8 af[4], bfr[4];
#pragma unroll
            for (int mi = 0; mi < 4; ++mi)
                af[mi] = *(const bf16x8*)&As[(wm + mi * 16 + col_l) * 64 + kk + quad * 8];
#pragma unroll
            for (int ni = 0; ni < 4; ++ni)
                bfr[ni] = *(const bf16x8*)&Bs[(wn + ni * 16 + col_l) * 64 + kk + quad * 8];
#pragma unroll
            for (int mi = 0; mi < 4; ++mi)
#pragma unroll
                for (int ni = 0; ni < 4; ++ni)
                    acc[mi][ni] = __builtin_amdgcn_mfma_f32_16x16x32_bf16(
                        af[mi], bfr[ni], acc[mi][ni], 0, 0, 0);
        }
    }

#pragma unroll
    for (int ni = 0; ni < 4; ++ni) {
        const int ncol = n0 + wn + ni * 16 + col_l;
        const float bv = bias[ncol];
#pragma unroll
        for (int mi = 0; mi < 4; ++mi) {
            const int mrow = m0 + wm + mi * 16 + quad * 4;
#pragma unroll
            for (int r = 0; r < 4; ++r)
                C[(size_t)(mrow + r) * Nn + ncol] = tanhf(acc[mi][ni][r] + bv);
        }
    }
}

// ---------------------------------------------------------------------------
// K5: unit-normalize H rows -> topk_h
// ---------------------------------------------------------------------------
__global__ __launch_bounds__(256)
void norm_rows(const float* __restrict__ H, float* __restrict__ out)
{
    const int row = blockIdx.x;
    const float* h = H + (size_t)row * SZ;
    const int t = threadIdx.x;
    const int wave = t >> 6, lane = t & 63;
    const float a = h[t], c = h[t + 256];
    float ss = a * a + c * c;
#pragma unroll
    for (int o = 32; o > 0; o >>= 1) ss += __shfl_down(ss, o);
    __shared__ float wsum[4];
    if (lane == 0) wsum[wave] = ss;
    __syncthreads();
    const float inv = rsqrtf(wsum[0] + wsum[1] + wsum[2] + wsum[3]);
    out[(size_t)row * SZ + t]       = a * inv;
    out[(size_t)row * SZ + t + 256] = c * inv;
}

// ---------------------------------------------------------------------------
extern "C" void kernel_launch(void* const* d_in, const int* in_sizes, int n_in,
                              void* d_out, int out_size, void* d_ws, size_t ws_size,
                              hipStream_t stream)
{
    const float* chart_h = (const float*)d_in[0];
    const float* chart_s = (const float*)d_in[1];
    const float* mat = (const float*)d_in[4];
    const float* Wc  = (const float*)d_in[5];
    const float* bc  = (const float*)d_in[6];
    float* out = (float*)d_out;

    // workspace (peak 125,704,192 B; proven ws >= 125,829,120 in r2):
    //   CH16  f16 [57856][512] @ 0            (59,244,544)  alive P0->K2
    //   T16   f16 [57856][512] @ 59,244,544   (59,244,544)  alive K1->K2
    //   MAT16 f16 [512][512]   @ 118,489,088  (   524,288)
    //   SALL  f32 [1536][64]   @ 119,013,376  (   393,216)
    //   FLAGS i32 [1536]       @ 119,406,592  (     6,144)
    //   X     bf16[3072][1024] @ 119,412,736  ( 6,291,456)  -> end 125,704,192
    //   WcT   bf16[512][1024]  @ 0            (reuses CH16 region after K2)
    //   H     f32 [3072][512]  @ 1,048,576    (reuses CH16 region after K2)
    char* ws = (char*)d_ws;
    _Float16* CH16  = (_Float16*)ws;
    _Float16* T16   = (_Float16*)(ws + 59244544);
    _Float16* MAT16 = (_Float16*)(ws + 118489088);
    float*    SALL  = (float*)(ws + 119013376);
    int*      FLAGS = (int*)(ws + 119406592);
    uint16_t* X     = (uint16_t*)(ws + 119412736);
    uint16_t* WcT   = (uint16_t*)ws;
    float*    H     = (float*)(ws + 1048576);

    // P0: f16 conversions (x16 chart, x64 mat); 14464*2048 = 29,622,272 exact
    prep<<<dim3(14464), 256, 0, stream>>>(chart_h, mat, CH16, MAT16);
    // K1: T' = CH16 @ MAT16^T  (57856x512x512, single-pass f16 MFMA)
    gemm_f16<<<dim3(4, 452), 256, 0, stream>>>(CH16, MAT16, T16, 57856, 512, 512);
    // K2: cheap scores + top3 + flag; outputs + X for clean positions
    score_topk<<<dim3(B_DIM * L_DIM), 256, 0, stream>>>(CH16, T16, chart_s, chart_h,
                                                        SALL, FLAGS, X, out);
    // (CH16/T16 dead from here; WcT/H overlap that region)
    transpose_wc<<<dim3(16, 8), 256, 0, stream>>>(Wc, WcT);
    // K3: exact refinement of flagged positions
    refine<<<dim3(B_DIM * L_DIM), 256, 0, stream>>>(chart_h, chart_s, mat,
                                                    SALL, FLAGS, X, out);
    // K4: H = tanh(X @ WcT^T + bc)
    gemm_compose<<<dim3(24, 4), 256, 0, stream>>>(X, WcT, bc, H, 3072, 512, 1024);
    // K5: topk_h = H / ||H||
    norm_rows<<<dim3(3072), 256, 0, stream>>>(H, out);
}

// Round 5
// 368.928 us; speedup vs baseline: 1.3581x; 1.3581x over previous
//
#include <hip/hip_runtime.h>
#include <cstdint>
#include <cstddef>

// ---------------------------------------------------------------------------
// Problem constants (LEVEL=16, LENGTH=64, TOPK=2, SIZE=512, BATCH=32)
// Inputs f32, outputs f32. Uniform absmax threshold 2.06 across outputs =>
// precision only matters for ORDERING near-ties (topk_n_idx needs |dn|<=2).
// Strategy: single-pass f16 MFMA for scores (err sigma ~6e-3) + exact f32
// refinement of positions whose cheap top-2/3 gaps are < DELTA=0.25.
//
// r4 lesson: refine was latency-bound (263 us, VALUBusy 1.3%) -- rolled loop,
// 16 broadcast ds_reads/iter, zero MLP at 1 block/CU. r5: wave-per-candidate,
// rh in regs, 1 ds_read/e, coalesced mat rows -> ~4 us/candidate VALU-bound.
// ---------------------------------------------------------------------------
#define B_DIM   32
#define L_DIM   48
#define NCELLS  904
#define SZ      512
#define NEGF    (-1e8f)
#define DELTA   0.25f

// d_out layout (f32), outputs concatenated flat in return order
#define OFF_S   1572864
#define OFF_N   1575936
#define OFF_L   1579008
#define OFF_R   1582080

typedef _Float16  f16x8 __attribute__((ext_vector_type(8)));
typedef float     f32x4 __attribute__((ext_vector_type(4)));

static __device__ __forceinline__ uint16_t f2bf(float f) {
    uint32_t u = __builtin_bit_cast(uint32_t, f);
    u += 0x7fffu + ((u >> 16) & 1u);
    return (uint16_t)(u >> 16);
}

#define GLD16(gp, lp) __builtin_amdgcn_global_load_lds(                        \
        (__attribute__((address_space(1))) void*)(gp),                         \
        (__attribute__((address_space(3))) void*)(lp), 16, 0, 0)

static __device__ __forceinline__ int level_off(int n) {
    return n * 64 - (n * (n - 1)) / 2;
}

// ---------------------------------------------------------------------------
// P0: chart_hf16 = f16(16*chart_h); matf16 = f16(64*mat)
// grid 14464 * 256 threads * 8 elems = 29,622,272 exactly.
// ---------------------------------------------------------------------------
__global__ __launch_bounds__(256)
void prep(const float* __restrict__ ch, const float* __restrict__ mat,
          _Float16* __restrict__ ch16, _Float16* __restrict__ mat16)
{
    const size_t i = ((size_t)blockIdx.x * 256 + threadIdx.x) * 8;
    const float4 a = *(const float4*)(ch + i);
    const float4 b = *(const float4*)(ch + i + 4);
    f16x8 v;
    v[0]=(_Float16)(a.x*16.f); v[1]=(_Float16)(a.y*16.f);
    v[2]=(_Float16)(a.z*16.f); v[3]=(_Float16)(a.w*16.f);
    v[4]=(_Float16)(b.x*16.f); v[5]=(_Float16)(b.y*16.f);
    v[6]=(_Float16)(b.z*16.f); v[7]=(_Float16)(b.w*16.f);
    *(f16x8*)(ch16 + i) = v;
    if (blockIdx.x < 128) {
        const size_t j = ((size_t)blockIdx.x * 256 + threadIdx.x) * 8;
        const float4 c = *(const float4*)(mat + j);
        const float4 d = *(const float4*)(mat + j + 4);
        f16x8 w;
        w[0]=(_Float16)(c.x*64.f); w[1]=(_Float16)(c.y*64.f);
        w[2]=(_Float16)(c.z*64.f); w[3]=(_Float16)(c.w*64.f);
        w[4]=(_Float16)(d.x*64.f); w[5]=(_Float16)(d.y*64.f);
        w[6]=(_Float16)(d.z*64.f); w[7]=(_Float16)(d.w*64.f);
        *(f16x8*)(mat16 + j) = w;
    }
}

// ---------------------------------------------------------------------------
// K1: T'[m,e] = sum_d A16[m,d]*B16[e,d]  (f16 in, f16 out, x1024 scaled)
// m97 structure: 128x128 tile, BK=64, grid x = n-tiles (fastest) for A reuse.
// ---------------------------------------------------------------------------
__global__ __launch_bounds__(256, 2)
void gemm_f16(const _Float16* __restrict__ A,
              const _Float16* __restrict__ Bm,
              _Float16* __restrict__ C,
              int M, int Nn, int Kk)
{
    __shared__ _Float16 As[128 * 64];
    __shared__ _Float16 Bs[128 * 64];

    const int tid  = threadIdx.x;
    const int wave = tid >> 6, lane = tid & 63;
    const int m0 = blockIdx.y * 128, n0 = blockIdx.x * 128;
    const int wm = (wave & 1) * 64, wn = (wave >> 1) * 64;
    const int col_l = lane & 15, quad = lane >> 4;
    const int lrow = lane >> 3;
    const int lcol = (lane & 7) * 8;

    f32x4 acc[4][4];
#pragma unroll
    for (int i = 0; i < 4; ++i)
#pragma unroll
        for (int j = 0; j < 4; ++j) acc[i][j] = (f32x4){0.f, 0.f, 0.f, 0.f};

    for (int k0 = 0; k0 < Kk; k0 += 64) {
        __syncthreads();
#pragma unroll
        for (int i = 0; i < 4; ++i) {
            const int q = wave * 4 + i;
            const int r = q * 8 + lrow;
            GLD16(A  + (size_t)(m0 + r) * Kk + k0 + lcol, (char*)As + q * 1024);
            GLD16(Bm + (size_t)(n0 + r) * Kk + k0 + lcol, (char*)Bs + q * 1024);
        }
        __syncthreads();
#pragma unroll
        for (int kk = 0; kk < 64; kk += 32) {
            f16x8 af[4], bfr[4];
#pragma unroll
            for (int mi = 0; mi < 4; ++mi)
                af[mi] = *(const f16x8*)&As[(wm + mi * 16 + col_l) * 64 + kk + quad * 8];
#pragma unroll
            for (int ni = 0; ni < 4; ++ni)
                bfr[ni] = *(const f16x8*)&Bs[(wn + ni * 16 + col_l) * 64 + kk + quad * 8];
#pragma unroll
            for (int mi = 0; mi < 4; ++mi)
#pragma unroll
                for (int ni = 0; ni < 4; ++ni)
                    acc[mi][ni] = __builtin_amdgcn_mfma_f32_16x16x32_f16(
                        af[mi], bfr[ni], acc[mi][ni], 0, 0, 0);
        }
    }

#pragma unroll
    for (int ni = 0; ni < 4; ++ni) {
        const int ncol = n0 + wn + ni * 16 + col_l;
#pragma unroll
        for (int mi = 0; mi < 4; ++mi) {
            const int mrow = m0 + wm + mi * 16 + quad * 4;
#pragma unroll
            for (int r = 0; r < 4; ++r)
                C[(size_t)(mrow + r) * Nn + ncol] = (_Float16)acc[mi][ni][r];
        }
    }
}

// ---------------------------------------------------------------------------
// shared epilogue: write the 8 scalar outputs + gather X rows
// ---------------------------------------------------------------------------
static __device__ __forceinline__ void emit_outputs(
    int row, int i1, int i2, float v1, float v2, float* out)
{
    out[OFF_S + row * 2 + 0] = v1;
    out[OFF_S + row * 2 + 1] = v2;
    out[OFF_N + row * 2 + 0] = (float)(i1 >> 2);
    out[OFF_N + row * 2 + 1] = (float)(i2 >> 2);
    out[OFF_L + row * 2 + 0] = (float)((i1 >> 1) & 1);
    out[OFF_L + row * 2 + 1] = (float)((i2 >> 1) & 1);
    out[OFF_R + row * 2 + 0] = (float)(i1 & 1);
    out[OFF_R + row * 2 + 1] = (float)(i2 & 1);
}

static __device__ __forceinline__ void gather_x(
    int row, int pos, int b, const int* top_z,
    const float* __restrict__ chart_h, uint16_t* __restrict__ X, int tid)
{
#pragma unroll
    for (int kq = 0; kq < 2; ++kq) {
        const int z = top_z[kq];
        const int n = z >> 2, lk = (z >> 1) & 1, rk = z & 1;
        const int lcell = level_off(n) + pos;
        const int rcell = level_off(15 - n) + pos + n + 1;
        const float* srcl = chart_h + ((size_t)(lk * B_DIM + b) * NCELLS + lcell) * SZ;
        const float* srcr = chart_h + ((size_t)(rk * B_DIM + b) * NCELLS + rcell) * SZ;
        uint16_t* dst = X + ((size_t)row * 2 + kq) * 1024;
        const int e = tid * 2;
        const float2 a = *(const float2*)(srcl + e);
        const float2 c = *(const float2*)(srcr + e);
        *(uint32_t*)(dst + e)       = (uint32_t)f2bf(a.x) | ((uint32_t)f2bf(a.y) << 16);
        *(uint32_t*)(dst + 512 + e) = (uint32_t)f2bf(c.x) | ((uint32_t)f2bf(c.y) << 16);
    }
}

// ---------------------------------------------------------------------------
// K2: cheap scores (f16 dot, f32 accum), top-3, flag near-ties; for clean
// positions emit outputs + gather X. Stores all 64 cheap scores for refine.
// ---------------------------------------------------------------------------
__global__ __launch_bounds__(256)
void score_topk(const _Float16* __restrict__ ch16,   // x16
                const _Float16* __restrict__ T16,    // x1024
                const float* __restrict__ chart_s,
                const float* __restrict__ chart_h,   // f32 (X gather)
                float* __restrict__ s_all,           // [1536][64]
                int* __restrict__ flags,             // [1536]
                uint16_t* __restrict__ X,
                float* __restrict__ out)
{
    const int b   = blockIdx.x / L_DIM;
    const int pos = blockIdx.x % L_DIM;
    const int row = blockIdx.x;
    const int wave = threadIdx.x >> 6, lane = threadIdx.x & 63;

    __shared__ float s_sh[64];
    __shared__ int top_z[2];
    __shared__ int flag_sh;

#pragma unroll
    for (int ni = 0; ni < 4; ++ni) {
        const int n = wave * 4 + ni;
        const int lcell = level_off(n) + pos;
        const int rcell = level_off(15 - n) + pos + n + 1;

        const f16x8 l0 = *(const f16x8*)(ch16 + ((size_t)(0 * B_DIM + b) * NCELLS + lcell) * SZ + lane * 8);
        const f16x8 l1 = *(const f16x8*)(ch16 + ((size_t)(1 * B_DIM + b) * NCELLS + lcell) * SZ + lane * 8);
        const f16x8 t0 = *(const f16x8*)(T16 + ((size_t)(0 * B_DIM + b) * NCELLS + rcell) * SZ + lane * 8);
        const f16x8 t1 = *(const f16x8*)(T16 + ((size_t)(1 * B_DIM + b) * NCELLS + rcell) * SZ + lane * 8);

        float d00 = 0.f, d01 = 0.f, d10 = 0.f, d11 = 0.f;
#pragma unroll
        for (int j = 0; j < 8; ++j) {
            const float a0 = (float)l0[j], a1 = (float)l1[j];
            const float c0 = (float)t0[j], c1 = (float)t1[j];
            d00 += a0 * c0; d01 += a0 * c1;
            d10 += a1 * c0; d11 += a1 * c1;
        }
#pragma unroll
        for (int o = 32; o > 0; o >>= 1) {
            d00 += __shfl_down(d00, o);
            d01 += __shfl_down(d01, o);
            d10 += __shfl_down(d10, o);
            d11 += __shfl_down(d11, o);
        }
        if (lane == 0) {
            const float ls0 = chart_s[(size_t)(0 * B_DIM + b) * NCELLS + lcell];
            const float ls1 = chart_s[(size_t)(1 * B_DIM + b) * NCELLS + lcell];
            const float rs0 = chart_s[(size_t)(0 * B_DIM + b) * NCELLS + rcell];
            const float rs1 = chart_s[(size_t)(1 * B_DIM + b) * NCELLS + rcell];
            const float inv = 1.0f / 16384.0f;       // undo 16 * 1024
            s_sh[n * 4 + 0] = d00 * inv + ls0 + rs0;
            s_sh[n * 4 + 1] = d01 * inv + ls0 + rs1;
            s_sh[n * 4 + 2] = d10 * inv + ls1 + rs0;
            s_sh[n * 4 + 3] = d11 * inv + ls1 + rs1;
        }
    }
    __syncthreads();

    if (threadIdx.x < 64) {
        float v = s_sh[lane];
        if (lane == 2 || lane == 3) v = NEGF;        // penalty mask
        s_all[(size_t)row * 64 + lane] = v;          // post-penalty, for refine
        float v1 = v; int i1 = lane;
#pragma unroll
        for (int o = 32; o > 0; o >>= 1) {
            float ov = __shfl_down(v1, o);
            int   oi = __shfl_down(i1, o);
            if (ov > v1 || (ov == v1 && oi < i1)) { v1 = ov; i1 = oi; }
        }
        v1 = __shfl(v1, 0); i1 = __shfl(i1, 0);
        float v2 = (lane == i1) ? -3.4e38f : v; int i2 = lane;
#pragma unroll
        for (int o = 32; o > 0; o >>= 1) {
            float ov = __shfl_down(v2, o);
            int   oi = __shfl_down(i2, o);
            if (ov > v2 || (ov == v2 && oi < i2)) { v2 = ov; i2 = oi; }
        }
        v2 = __shfl(v2, 0); i2 = __shfl(i2, 0);
        float v3 = (lane == i1 || lane == i2) ? -3.4e38f : v;
#pragma unroll
        for (int o = 32; o > 0; o >>= 1) {
            const float ov = __shfl_down(v3, o);
            if (ov > v3) v3 = ov;
        }
        if (lane == 0) {
            const int f = (v1 - v2 < DELTA) || (v2 - v3 < DELTA);
            flags[row] = f;
            flag_sh = f;
            top_z[0] = i1; top_z[1] = i2;
            if (!f) emit_outputs(row, i1, i2, v1, v2, out);
        }
    }
    __syncthreads();

    if (!flag_sh)
        gather_x(row, pos, b, top_z, chart_h, X, threadIdx.x);
}

// ---------------------------------------------------------------------------
// K3: exact f32 refinement of flagged positions -- wave-per-candidate.
// Lane owns rh[8*lane..+8) in regs; lh staged to the wave's LDS row (one
// broadcast ds_read per e); mat rows read coalesced (2KB/row/wave).
// ~5K VALU instr per candidate per wave, candidates parallel across 4 waves.
// ---------------------------------------------------------------------------
__global__ __launch_bounds__(256)
void refine(const float* __restrict__ chart_h,
            const float* __restrict__ chart_s,
            const float* __restrict__ mat,
            const float* __restrict__ s_all,
            const int* __restrict__ flags,
            uint16_t* __restrict__ X,
            float* __restrict__ out)
{
    const int row = blockIdx.x;
    if (flags[row] == 0) return;
    const int b = row / L_DIM, pos = row % L_DIM;
    const int t = threadIdx.x;
    const int wave = t >> 6, lane = t & 63;

    __shared__ float sc[64];
    __shared__ int   cz[64];
    __shared__ int   ncand_sh;
    __shared__ float lh_sh[4][512];
    __shared__ float exval[64];
    __shared__ int   top_z[2];

    if (t < 64) sc[t] = s_all[(size_t)row * 64 + t];
    __syncthreads();
    if (t == 0) {
        float v1 = -3.4e38f; int i1 = -1;
        for (int z = 0; z < 64; ++z) if (sc[z] > v1) { v1 = sc[z]; i1 = z; }
        float v2 = -3.4e38f;
        for (int z = 0; z < 64; ++z) if (z != i1 && sc[z] > v2) v2 = sc[z];
        int nc = 0;
        for (int z = 0; z < 64; ++z) if (sc[z] >= v2 - DELTA) cz[nc++] = z;
        ncand_sh = nc;
    }
    __syncthreads();
    const int nc = ncand_sh;

    for (int c = wave; c < nc; c += 4) {
        const int z = cz[c];
        const int n = z >> 2, lk = (z >> 1) & 1, rk = z & 1;
        const int lcell = level_off(n) + pos;
        const int rcell = level_off(15 - n) + pos + n + 1;
        const float* lhp = chart_h + ((size_t)(lk * B_DIM + b) * NCELLS + lcell) * SZ;
        const float* rhp = chart_h + ((size_t)(rk * B_DIM + b) * NCELLS + rcell) * SZ;

        // stage lh into this wave's LDS row (wave-coherent, no barrier needed)
        *(float4*)&lh_sh[wave][lane * 8]     = *(const float4*)(lhp + lane * 8);
        *(float4*)&lh_sh[wave][lane * 8 + 4] = *(const float4*)(lhp + lane * 8 + 4);
        // rh chunk in registers
        const float4 r0 = *(const float4*)(rhp + lane * 8);
        const float4 r1 = *(const float4*)(rhp + lane * 8 + 4);

        const float* mb = mat + lane * 8;
        float acc0 = 0.f, acc1 = 0.f, acc2 = 0.f, acc3 = 0.f;
#pragma unroll 2
        for (int e = 0; e < 512; e += 4) {
            const float4 a0 = *(const float4*)(mb + (size_t)(e + 0) * 512);
            const float4 b0 = *(const float4*)(mb + (size_t)(e + 0) * 512 + 4);
            const float4 a1 = *(const float4*)(mb + (size_t)(e + 1) * 512);
            const float4 b1 = *(const float4*)(mb + (size_t)(e + 1) * 512 + 4);
            const float4 a2 = *(const float4*)(mb + (size_t)(e + 2) * 512);
            const float4 b2 = *(const float4*)(mb + (size_t)(e + 2) * 512 + 4);
            const float4 a3 = *(const float4*)(mb + (size_t)(e + 3) * 512);
            const float4 b3 = *(const float4*)(mb + (size_t)(e + 3) * 512 + 4);
            const float l0 = lh_sh[wave][e + 0];
            const float l1 = lh_sh[wave][e + 1];
            const float l2 = lh_sh[wave][e + 2];
            const float l3 = lh_sh[wave][e + 3];
            acc0 += l0 * (a0.x*r0.x + a0.y*r0.y + a0.z*r0.z + a0.w*r0.w
                        + b0.x*r1.x + b0.y*r1.y + b0.z*r1.z + b0.w*r1.w);
            acc1 += l1 * (a1.x*r0.x + a1.y*r0.y + a1.z*r0.z + a1.w*r0.w
                        + b1.x*r1.x + b1.y*r1.y + b1.z*r1.z + b1.w*r1.w);
            acc2 += l2 * (a2.x*r0.x + a2.y*r0.y + a2.z*r0.z + a2.w*r0.w
                        + b2.x*r1.x + b2.y*r1.y + b2.z*r1.z + b2.w*r1.w);
            acc3 += l3 * (a3.x*r0.x + a3.y*r0.y + a3.z*r0.z + a3.w*r0.w
                        + b3.x*r1.x + b3.y*r1.y + b3.z*r1.z + b3.w*r1.w);
        }
        float s = (acc0 + acc1) + (acc2 + acc3);
#pragma unroll
        for (int o = 32; o > 0; o >>= 1) s += __shfl_down(s, o);
        if (lane == 0) {
            const float ls = chart_s[(size_t)(lk * B_DIM + b) * NCELLS + lcell];
            const float rs = chart_s[(size_t)(rk * B_DIM + b) * NCELLS + rcell];
            exval[c] = s + ls + rs;
        }
    }
    __syncthreads();

    if (t == 0) {
        float v1 = -3.4e38f; int c1 = -1;
        for (int c = 0; c < nc; ++c) if (exval[c] > v1) { v1 = exval[c]; c1 = c; }
        float v2 = -3.4e38f; int c2 = -1;
        for (int c = 0; c < nc; ++c) if (c != c1 && exval[c] > v2) { v2 = exval[c]; c2 = c; }
        const int i1 = cz[c1], i2 = cz[c2];
        top_z[0] = i1; top_z[1] = i2;
        emit_outputs(row, i1, i2, v1, v2, out);
    }
    __syncthreads();
    gather_x(row, pos, b, top_z, chart_h, X, t);
}

// ---------------------------------------------------------------------------
// transpose_wc: WcT[o][i] = bf16(Wc[i][o])
// ---------------------------------------------------------------------------
__global__ __launch_bounds__(256)
void transpose_wc(const float* __restrict__ Wc, uint16_t* __restrict__ WcT)
{
    __shared__ float tbuf[64][65];
    const int i0 = blockIdx.x * 64;
    const int o0 = blockIdx.y * 64;
    const int c = threadIdx.x & 63, r4 = threadIdx.x >> 6;
    for (int rr = r4; rr < 64; rr += 4)
        tbuf[rr][c] = Wc[(size_t)(i0 + rr) * 512 + o0 + c];
    __syncthreads();
    for (int rr = r4; rr < 64; rr += 4)
        WcT[(size_t)(o0 + rr) * 1024 + i0 + c] = f2bf(tbuf[c][rr]);
}

// ---------------------------------------------------------------------------
// K4: H = tanh(X @ WcT^T + bc)  (bf16 in, f32 out)
// ---------------------------------------------------------------------------
typedef __bf16 bf16x8 __attribute__((ext_vector_type(8)));

__global__ __launch_bounds__(256, 2)
void gemm_compose(const uint16_t* __restrict__ A,
                  const uint16_t* __restrict__ Bm,
                  const float* __restrict__ bias,
                  float* __restrict__ C,
                  int M, int Nn, int Kk)
{
    __shared__ uint16_t As[128 * 64];
    __shared__ uint16_t Bs[128 * 64];

    const int tid  = threadIdx.x;
    const int wave = tid >> 6, lane = tid & 63;
    const int m0 = blockIdx.x * 128, n0 = blockIdx.y * 128;
    const int wm = (wave & 1) * 64, wn = (wave >> 1) * 64;
    const int col_l = lane & 15, quad = lane >> 4;
    const int lrow = lane >> 3;
    const int lcol = (lane & 7) * 8;

    f32x4 acc[4][4];
#pragma unroll
    for (int i = 0; i < 4; ++i)
#pragma unroll
        for (int j = 0; j < 4; ++j) acc[i][j] = (f32x4){0.f, 0.f, 0.f, 0.f};

    for (int k0 = 0; k0 < Kk; k0 += 64) {
        __syncthreads();
#pragma unroll
        for (int i = 0; i < 4; ++i) {
            const int q = wave * 4 + i;
            const int r = q * 8 + lrow;
            GLD16(A  + (size_t)(m0 + r) * Kk + k0 + lcol, (char*)As + q * 1024);
            GLD16(Bm + (size_t)(n0 + r) * Kk + k0 + lcol, (char*)Bs + q * 1024);
        }
        __syncthreads();
#pragma unroll
        for (int kk = 0; kk < 64; kk += 32) {
            bf16x8 af[4], bfr[4];
#pragma unroll
            for (int mi = 0; mi < 4; ++mi)
                af[mi] = *(const bf16x8*)&As[(wm + mi * 16 + col_l) * 64 + kk + quad * 8];
#pragma unroll
            for (int ni = 0; ni < 4; ++ni)
                bfr[ni] = *(const bf16x8*)&Bs[(wn + ni * 16 + col_l) * 64 + kk + quad * 8];
#pragma unroll
            for (int mi = 0; mi < 4; ++mi)
#pragma unroll
                for (int ni = 0; ni < 4; ++ni)
                    acc[mi][ni] = __builtin_amdgcn_mfma_f32_16x16x32_bf16(
                        af[mi], bfr[ni], acc[mi][ni], 0, 0, 0);
        }
    }

#pragma unroll
    for (int ni = 0; ni < 4; ++ni) {
        const int ncol = n0 + wn + ni * 16 + col_l;
        const float bv = bias[ncol];
#pragma unroll
        for (int mi = 0; mi < 4; ++mi) {
            const int mrow = m0 + wm + mi * 16 + quad * 4;
#pragma unroll
            for (int r = 0; r < 4; ++r)
                C[(size_t)(mrow + r) * Nn + ncol] = tanhf(acc[mi][ni][r] + bv);
        }
    }
}

// ---------------------------------------------------------------------------
// K5: unit-normalize H rows -> topk_h
// ---------------------------------------------------------------------------
__global__ __launch_bounds__(256)
void norm_rows(const float* __restrict__ H, float* __restrict__ out)
{
    const int row = blockIdx.x;
    const float* h = H + (size_t)row * SZ;
    const int t = threadIdx.x;
    const int wave = t >> 6, lane = t & 63;
    const float a = h[t], c = h[t + 256];
    float ss = a * a + c * c;
#pragma unroll
    for (int o = 32; o > 0; o >>= 1) ss += __shfl_down(ss, o);
    __shared__ float wsum[4];
    if (lane == 0) wsum[wave] = ss;
    __syncthreads();
    const float inv = rsqrtf(wsum[0] + wsum[1] + wsum[2] + wsum[3]);
    out[(size_t)row * SZ + t]       = a * inv;
    out[(size_t)row * SZ + t + 256] = c * inv;
}

// ---------------------------------------------------------------------------
extern "C" void kernel_launch(void* const* d_in, const int* in_sizes, int n_in,
                              void* d_out, int out_size, void* d_ws, size_t ws_size,
                              hipStream_t stream)
{
    const float* chart_h = (const float*)d_in[0];
    const float* chart_s = (const float*)d_in[1];
    const float* mat = (const float*)d_in[4];
    const float* Wc  = (const float*)d_in[5];
    const float* bc  = (const float*)d_in[6];
    float* out = (float*)d_out;

    // workspace (peak 125,704,192 B; proven ws >= 125,829,120 in r2):
    //   CH16  f16 [57856][512] @ 0            (59,244,544)  alive P0->K2
    //   T16   f16 [57856][512] @ 59,244,544   (59,244,544)  alive K1->K2
    //   MAT16 f16 [512][512]   @ 118,489,088  (   524,288)
    //   SALL  f32 [1536][64]   @ 119,013,376  (   393,216)
    //   FLAGS i32 [1536]       @ 119,406,592  (     6,144)
    //   X     bf16[3072][1024] @ 119,412,736  ( 6,291,456)  -> end 125,704,192
    //   WcT   bf16[512][1024]  @ 0            (reuses CH16 region after K2)
    //   H     f32 [3072][512]  @ 1,048,576    (reuses CH16 region after K2)
    char* ws = (char*)d_ws;
    _Float16* CH16  = (_Float16*)ws;
    _Float16* T16   = (_Float16*)(ws + 59244544);
    _Float16* MAT16 = (_Float16*)(ws + 118489088);
    float*    SALL  = (float*)(ws + 119013376);
    int*      FLAGS = (int*)(ws + 119406592);
    uint16_t* X     = (uint16_t*)(ws + 119412736);
    uint16_t* WcT   = (uint16_t*)ws;
    float*    H     = (float*)(ws + 1048576);

    // P0: f16 conversions (x16 chart, x64 mat); 14464*2048 = 29,622,272 exact
    prep<<<dim3(14464), 256, 0, stream>>>(chart_h, mat, CH16, MAT16);
    // K1: T' = CH16 @ MAT16^T  (57856x512x512, single-pass f16 MFMA)
    gemm_f16<<<dim3(4, 452), 256, 0, stream>>>(CH16, MAT16, T16, 57856, 512, 512);
    // K2: cheap scores + top3 + flag; outputs + X for clean positions
    score_topk<<<dim3(B_DIM * L_DIM), 256, 0, stream>>>(CH16, T16, chart_s, chart_h,
                                                        SALL, FLAGS, X, out);
    // (CH16/T16 dead from here; WcT/H overlap that region)
    transpose_wc<<<dim3(16, 8), 256, 0, stream>>>(Wc, WcT);
    // K3: exact refinement of flagged positions (wave-per-candidate)
    refine<<<dim3(B_DIM * L_DIM), 256, 0, stream>>>(chart_h, chart_s, mat,
                                                    SALL, FLAGS, X, out);
    // K4: H = tanh(X @ WcT^T + bc)
    gemm_compose<<<dim3(24, 4), 256, 0, stream>>>(X, WcT, bc, H, 3072, 512, 1024);
    // K5: topk_h = H / ||H||
    norm_rows<<<dim3(3072), 256, 0, stream>>>(H, out);
}

// Round 6
// 324.049 us; speedup vs baseline: 1.5462x; 1.1385x over previous
//
#include <hip/hip_runtime.h>
#include <cstdint>
#include <cstddef>

// ---------------------------------------------------------------------------
// Problem constants (LEVEL=16, LENGTH=64, TOPK=2, SIZE=512, BATCH=32)
// Inputs f32, outputs f32. Uniform absmax threshold 2.06 across outputs =>
// precision only matters for ORDERING near-ties (topk_n_idx needs |dn|<=2).
// Cheap path: single-pass f16 MFMA scores (err sigma ~0.02). Rows whose
// cheap top-2/3 gaps < DELTA=0.25 get exact f32 refinement of the candidate
// set {z: cheap[z] >= cheap_top2 - DELTA} (contains true top-2 for
// DELTA > 2*errmax).
//
// r5 lesson: block-per-row refine was latency-bound (80-100us, VALUBusy 2.6%,
// occupancy 2.6%): ~100 active blocks, serialized L2 loads, full 1MB mat
// swept per candidate. r6: compacted work queue (ballot in score_topk),
// block-per-ITEM-PAIR eval (mat shared by both items), per-row pick kernel.
// ---------------------------------------------------------------------------
#define B_DIM   32
#define L_DIM   48
#define NCELLS  904
#define SZ      512
#define NEGF    (-1e8f)
#define DELTA   0.25f
#define MAXC    32          // max candidates per row kept (z-ascending)

// d_out layout (f32), outputs concatenated flat in return order
#define OFF_S   1572864
#define OFF_N   1575936
#define OFF_L   1579008
#define OFF_R   1582080

typedef _Float16  f16x8 __attribute__((ext_vector_type(8)));
typedef float     f32x4 __attribute__((ext_vector_type(4)));

static __device__ __forceinline__ uint16_t f2bf(float f) {
    uint32_t u = __builtin_bit_cast(uint32_t, f);
    u += 0x7fffu + ((u >> 16) & 1u);
    return (uint16_t)(u >> 16);
}

#define GLD16(gp, lp) __builtin_amdgcn_global_load_lds(                        \
        (__attribute__((address_space(1))) void*)(gp),                         \
        (__attribute__((address_space(3))) void*)(lp), 16, 0, 0)

static __device__ __forceinline__ int level_off(int n) {
    return n * 64 - (n * (n - 1)) / 2;
}

// ---------------------------------------------------------------------------
// P0: chart_hf16 = f16(16*chart_h); matf16 = f16(64*mat)
// ---------------------------------------------------------------------------
__global__ __launch_bounds__(256)
void prep(const float* __restrict__ ch, const float* __restrict__ mat,
          _Float16* __restrict__ ch16, _Float16* __restrict__ mat16)
{
    const size_t i = ((size_t)blockIdx.x * 256 + threadIdx.x) * 8;
    const float4 a = *(const float4*)(ch + i);
    const float4 b = *(const float4*)(ch + i + 4);
    f16x8 v;
    v[0]=(_Float16)(a.x*16.f); v[1]=(_Float16)(a.y*16.f);
    v[2]=(_Float16)(a.z*16.f); v[3]=(_Float16)(a.w*16.f);
    v[4]=(_Float16)(b.x*16.f); v[5]=(_Float16)(b.y*16.f);
    v[6]=(_Float16)(b.z*16.f); v[7]=(_Float16)(b.w*16.f);
    *(f16x8*)(ch16 + i) = v;
    if (blockIdx.x < 128) {
        const size_t j = ((size_t)blockIdx.x * 256 + threadIdx.x) * 8;
        const float4 c = *(const float4*)(mat + j);
        const float4 d = *(const float4*)(mat + j + 4);
        f16x8 w;
        w[0]=(_Float16)(c.x*64.f); w[1]=(_Float16)(c.y*64.f);
        w[2]=(_Float16)(c.z*64.f); w[3]=(_Float16)(c.w*64.f);
        w[4]=(_Float16)(d.x*64.f); w[5]=(_Float16)(d.y*64.f);
        w[6]=(_Float16)(d.z*64.f); w[7]=(_Float16)(d.w*64.f);
        *(f16x8*)(mat16 + j) = w;
    }
}

// ---------------------------------------------------------------------------
// K1: T'[m,e] = sum_d A16[m,d]*B16[e,d]  (f16 in, f16 out, x1024 scaled)
// ---------------------------------------------------------------------------
__global__ __launch_bounds__(256, 2)
void gemm_f16(const _Float16* __restrict__ A,
              const _Float16* __restrict__ Bm,
              _Float16* __restrict__ C,
              int M, int Nn, int Kk)
{
    __shared__ _Float16 As[128 * 64];
    __shared__ _Float16 Bs[128 * 64];

    const int tid  = threadIdx.x;
    const int wave = tid >> 6, lane = tid & 63;
    const int m0 = blockIdx.y * 128, n0 = blockIdx.x * 128;
    const int wm = (wave & 1) * 64, wn = (wave >> 1) * 64;
    const int col_l = lane & 15, quad = lane >> 4;
    const int lrow = lane >> 3;
    const int lcol = (lane & 7) * 8;

    f32x4 acc[4][4];
#pragma unroll
    for (int i = 0; i < 4; ++i)
#pragma unroll
        for (int j = 0; j < 4; ++j) acc[i][j] = (f32x4){0.f, 0.f, 0.f, 0.f};

    for (int k0 = 0; k0 < Kk; k0 += 64) {
        __syncthreads();
#pragma unroll
        for (int i = 0; i < 4; ++i) {
            const int q = wave * 4 + i;
            const int r = q * 8 + lrow;
            GLD16(A  + (size_t)(m0 + r) * Kk + k0 + lcol, (char*)As + q * 1024);
            GLD16(Bm + (size_t)(n0 + r) * Kk + k0 + lcol, (char*)Bs + q * 1024);
        }
        __syncthreads();
#pragma unroll
        for (int kk = 0; kk < 64; kk += 32) {
            f16x8 af[4], bfr[4];
#pragma unroll
            for (int mi = 0; mi < 4; ++mi)
                af[mi] = *(const f16x8*)&As[(wm + mi * 16 + col_l) * 64 + kk + quad * 8];
#pragma unroll
            for (int ni = 0; ni < 4; ++ni)
                bfr[ni] = *(const f16x8*)&Bs[(wn + ni * 16 + col_l) * 64 + kk + quad * 8];
#pragma unroll
            for (int mi = 0; mi < 4; ++mi)
#pragma unroll
                for (int ni = 0; ni < 4; ++ni)
                    acc[mi][ni] = __builtin_amdgcn_mfma_f32_16x16x32_f16(
                        af[mi], bfr[ni], acc[mi][ni], 0, 0, 0);
        }
    }

#pragma unroll
    for (int ni = 0; ni < 4; ++ni) {
        const int ncol = n0 + wn + ni * 16 + col_l;
#pragma unroll
        for (int mi = 0; mi < 4; ++mi) {
            const int mrow = m0 + wm + mi * 16 + quad * 4;
#pragma unroll
            for (int r = 0; r < 4; ++r)
                C[(size_t)(mrow + r) * Nn + ncol] = (_Float16)acc[mi][ni][r];
        }
    }
}

// ---------------------------------------------------------------------------
// shared epilogue helpers
// ---------------------------------------------------------------------------
static __device__ __forceinline__ void emit_outputs(
    int row, int i1, int i2, float v1, float v2, float* out)
{
    out[OFF_S + row * 2 + 0] = v1;
    out[OFF_S + row * 2 + 1] = v2;
    out[OFF_N + row * 2 + 0] = (float)(i1 >> 2);
    out[OFF_N + row * 2 + 1] = (float)(i2 >> 2);
    out[OFF_L + row * 2 + 0] = (float)((i1 >> 1) & 1);
    out[OFF_L + row * 2 + 1] = (float)((i2 >> 1) & 1);
    out[OFF_R + row * 2 + 0] = (float)(i1 & 1);
    out[OFF_R + row * 2 + 1] = (float)(i2 & 1);
}

static __device__ __forceinline__ void gather_x(
    int row, int pos, int b, const int* top_z,
    const float* __restrict__ chart_h, uint16_t* __restrict__ X, int tid)
{
#pragma unroll
    for (int kq = 0; kq < 2; ++kq) {
        const int z = top_z[kq];
        const int n = z >> 2, lk = (z >> 1) & 1, rk = z & 1;
        const int lcell = level_off(n) + pos;
        const int rcell = level_off(15 - n) + pos + n + 1;
        const float* srcl = chart_h + ((size_t)(lk * B_DIM + b) * NCELLS + lcell) * SZ;
        const float* srcr = chart_h + ((size_t)(rk * B_DIM + b) * NCELLS + rcell) * SZ;
        uint16_t* dst = X + ((size_t)row * 2 + kq) * 1024;
        const int e = tid * 2;
        const float2 a = *(const float2*)(srcl + e);
        const float2 c = *(const float2*)(srcr + e);
        *(uint32_t*)(dst + e)       = (uint32_t)f2bf(a.x) | ((uint32_t)f2bf(a.y) << 16);
        *(uint32_t*)(dst + 512 + e) = (uint32_t)f2bf(c.x) | ((uint32_t)f2bf(c.y) << 16);
    }
}

// ---------------------------------------------------------------------------
// K2: cheap scores, top-3, near-tie flagging + candidate queue (ballot
// compaction, z-ascending, one atomicAdd per flagged row). Clean rows emit
// outputs + gather X here.
// ---------------------------------------------------------------------------
__global__ __launch_bounds__(256)
void score_topk(const _Float16* __restrict__ ch16,   // x16
                const _Float16* __restrict__ T16,    // x1024
                const float* __restrict__ chart_s,
                const float* __restrict__ chart_h,   // f32 (X gather)
                uint32_t* __restrict__ items,        // queue entries (row<<6|z)
                int* __restrict__ rowbase,           // [1536]
                int* __restrict__ counter,           // 1 int, pre-zeroed
                int* __restrict__ flags,             // [1536]: nc (0 = clean)
                uint16_t* __restrict__ X,
                float* __restrict__ out)
{
    const int b   = blockIdx.x / L_DIM;
    const int pos = blockIdx.x % L_DIM;
    const int row = blockIdx.x;
    const int wave = threadIdx.x >> 6, lane = threadIdx.x & 63;

    __shared__ float s_sh[64];
    __shared__ int top_z[2];
    __shared__ int flag_sh;

#pragma unroll
    for (int ni = 0; ni < 4; ++ni) {
        const int n = wave * 4 + ni;
        const int lcell = level_off(n) + pos;
        const int rcell = level_off(15 - n) + pos + n + 1;

        const f16x8 l0 = *(const f16x8*)(ch16 + ((size_t)(0 * B_DIM + b) * NCELLS + lcell) * SZ + lane * 8);
        const f16x8 l1 = *(const f16x8*)(ch16 + ((size_t)(1 * B_DIM + b) * NCELLS + lcell) * SZ + lane * 8);
        const f16x8 t0 = *(const f16x8*)(T16 + ((size_t)(0 * B_DIM + b) * NCELLS + rcell) * SZ + lane * 8);
        const f16x8 t1 = *(const f16x8*)(T16 + ((size_t)(1 * B_DIM + b) * NCELLS + rcell) * SZ + lane * 8);

        float d00 = 0.f, d01 = 0.f, d10 = 0.f, d11 = 0.f;
#pragma unroll
        for (int j = 0; j < 8; ++j) {
            const float a0 = (float)l0[j], a1 = (float)l1[j];
            const float c0 = (float)t0[j], c1 = (float)t1[j];
            d00 += a0 * c0; d01 += a0 * c1;
            d10 += a1 * c0; d11 += a1 * c1;
        }
#pragma unroll
        for (int o = 32; o > 0; o >>= 1) {
            d00 += __shfl_down(d00, o);
            d01 += __shfl_down(d01, o);
            d10 += __shfl_down(d10, o);
            d11 += __shfl_down(d11, o);
        }
        if (lane == 0) {
            const float ls0 = chart_s[(size_t)(0 * B_DIM + b) * NCELLS + lcell];
            const float ls1 = chart_s[(size_t)(1 * B_DIM + b) * NCELLS + lcell];
            const float rs0 = chart_s[(size_t)(0 * B_DIM + b) * NCELLS + rcell];
            const float rs1 = chart_s[(size_t)(1 * B_DIM + b) * NCELLS + rcell];
            const float inv = 1.0f / 16384.0f;       // undo 16 * 1024
            s_sh[n * 4 + 0] = d00 * inv + ls0 + rs0;
            s_sh[n * 4 + 1] = d01 * inv + ls0 + rs1;
            s_sh[n * 4 + 2] = d10 * inv + ls1 + rs0;
            s_sh[n * 4 + 3] = d11 * inv + ls1 + rs1;
        }
    }
    __syncthreads();

    if (threadIdx.x < 64) {
        float v = s_sh[lane];
        if (lane == 2 || lane == 3) v = NEGF;        // penalty mask
        float v1 = v; int i1 = lane;
#pragma unroll
        for (int o = 32; o > 0; o >>= 1) {
            float ov = __shfl_down(v1, o);
            int   oi = __shfl_down(i1, o);
            if (ov > v1 || (ov == v1 && oi < i1)) { v1 = ov; i1 = oi; }
        }
        v1 = __shfl(v1, 0); i1 = __shfl(i1, 0);
        float v2 = (lane == i1) ? -3.4e38f : v; int i2 = lane;
#pragma unroll
        for (int o = 32; o > 0; o >>= 1) {
            float ov = __shfl_down(v2, o);
            int   oi = __shfl_down(i2, o);
            if (ov > v2 || (ov == v2 && oi < i2)) { v2 = ov; i2 = oi; }
        }
        v2 = __shfl(v2, 0); i2 = __shfl(i2, 0);
        float v3 = (lane == i1 || lane == i2) ? -3.4e38f : v;
#pragma unroll
        for (int o = 32; o > 0; o >>= 1) {
            const float ov = __shfl_down(v3, o);
            if (ov > v3) v3 = ov;
        }
        v3 = __shfl(v3, 0);

        const int f = (v1 - v2 < DELTA) || (v2 - v3 < DELTA);
        const bool cand = (v >= v2 - DELTA);
        const unsigned long long mask = __ballot(cand);
        const int nc_full = __popcll(mask);
        const int nc = nc_full < MAXC ? nc_full : MAXC;
        int base = 0;
        if (lane == 0) {
            flags[row] = f ? nc : 0;
            flag_sh = f;
            if (f) base = atomicAdd(counter, nc);
            rowbase[row] = base;
            top_z[0] = i1; top_z[1] = i2;
            if (!f) emit_outputs(row, i1, i2, v1, v2, out);
        }
        base = __shfl(base, 0);
        if (f && cand) {
            const int rank = __popcll(mask & ((1ull << lane) - 1ull));
            if (rank < MAXC) items[base + rank] = ((uint32_t)row << 6) | (uint32_t)lane;
        }
    }
    __syncthreads();

    if (!flag_sh)
        gather_x(row, pos, b, top_z, chart_h, X, threadIdx.x);
}

// ---------------------------------------------------------------------------
// K3a: exact f32 eval, block per ITEM PAIR (both items share the 1MB mat
// sweep). Waves split the e-range (128 rows each); lane owns rh[8*lane..+8)
// for both items in regs; lh staged in LDS.
// ---------------------------------------------------------------------------
__global__ __launch_bounds__(256)
void refine_eval(const float* __restrict__ chart_h,
                 const float* __restrict__ chart_s,
                 const float* __restrict__ mat,
                 const uint32_t* __restrict__ items,
                 const int* __restrict__ counter,
                 float* __restrict__ exval)
{
    const int total = *counter;
    const int t = threadIdx.x;
    const int wave = t >> 6, lane = t & 63;

    __shared__ float lh_sh[2][512];
    __shared__ float psum[2][4];

    for (int p = blockIdx.x; 2 * p < total; p += gridDim.x) {
        const int it0 = 2 * p;
        const int it1v = (2 * p + 1 < total);
        const uint32_t item0 = items[it0];
        const uint32_t item1 = it1v ? items[it0 + 1] : item0;

        // decode both items
        int rowA = item0 >> 6, zA = item0 & 63;
        int bA = rowA / L_DIM, posA = rowA % L_DIM;
        int nA = zA >> 2, lkA = (zA >> 1) & 1, rkA = zA & 1;
        int lcA = level_off(nA) + posA, rcA = level_off(15 - nA) + posA + nA + 1;
        int rowB = item1 >> 6, zB = item1 & 63;
        int bB = rowB / L_DIM, posB = rowB % L_DIM;
        int nB = zB >> 2, lkB = (zB >> 1) & 1, rkB = zB & 1;
        int lcB = level_off(nB) + posB, rcB = level_off(15 - nB) + posB + nB + 1;

        const float* lhA = chart_h + ((size_t)(lkA * B_DIM + bA) * NCELLS + lcA) * SZ;
        const float* rhA = chart_h + ((size_t)(rkA * B_DIM + bA) * NCELLS + rcA) * SZ;
        const float* lhB = chart_h + ((size_t)(lkB * B_DIM + bB) * NCELLS + lcB) * SZ;
        const float* rhB = chart_h + ((size_t)(rkB * B_DIM + bB) * NCELLS + rcB) * SZ;

        __syncthreads();                 // LDS free from previous pair
        lh_sh[0][t] = lhA[t]; lh_sh[0][t + 256] = lhA[t + 256];
        lh_sh[1][t] = lhB[t]; lh_sh[1][t + 256] = lhB[t + 256];
        const float4 rA0 = *(const float4*)(rhA + lane * 8);
        const float4 rA1 = *(const float4*)(rhA + lane * 8 + 4);
        const float4 rB0 = *(const float4*)(rhB + lane * 8);
        const float4 rB1 = *(const float4*)(rhB + lane * 8 + 4);
        __syncthreads();

        const float* mb = mat + (size_t)(wave * 128) * 512 + lane * 8;
        float a00 = 0.f, a01 = 0.f, b00 = 0.f, b01 = 0.f;
        for (int e = 0; e < 128; e += 2) {
            const float4 m0 = *(const float4*)(mb + (size_t)(e + 0) * 512);
            const float4 m1 = *(const float4*)(mb + (size_t)(e + 0) * 512 + 4);
            const float4 m2 = *(const float4*)(mb + (size_t)(e + 1) * 512);
            const float4 m3 = *(const float4*)(mb + (size_t)(e + 1) * 512 + 4);
            const int eg = wave * 128 + e;
            const float lA0 = lh_sh[0][eg],     lB0 = lh_sh[1][eg];
            const float lA1 = lh_sh[0][eg + 1], lB1 = lh_sh[1][eg + 1];
            const float dA0 = m0.x*rA0.x + m0.y*rA0.y + m0.z*rA0.z + m0.w*rA0.w
                            + m1.x*rA1.x + m1.y*rA1.y + m1.z*rA1.z + m1.w*rA1.w;
            const float dB0 = m0.x*rB0.x + m0.y*rB0.y + m0.z*rB0.z + m0.w*rB0.w
                            + m1.x*rB1.x + m1.y*rB1.y + m1.z*rB1.z + m1.w*rB1.w;
            const float dA1 = m2.x*rA0.x + m2.y*rA0.y + m2.z*rA0.z + m2.w*rA0.w
                            + m3.x*rA1.x + m3.y*rA1.y + m3.z*rA1.z + m3.w*rA1.w;
            const float dB1 = m2.x*rB0.x + m2.y*rB0.y + m2.z*rB0.z + m2.w*rB0.w
                            + m3.x*rB1.x + m3.y*rB1.y + m3.z*rB1.z + m3.w*rB1.w;
            a00 += lA0 * dA0; a01 += lA1 * dA1;
            b00 += lB0 * dB0; b01 += lB1 * dB1;
        }
        float sA = a00 + a01, sB = b00 + b01;
#pragma unroll
        for (int o = 32; o > 0; o >>= 1) {
            sA += __shfl_down(sA, o);
            sB += __shfl_down(sB, o);
        }
        if (lane == 0) { psum[0][wave] = sA; psum[1][wave] = sB; }
        __syncthreads();
        if (t == 0) {
            const float lsA = chart_s[(size_t)(lkA * B_DIM + bA) * NCELLS + lcA];
            const float rsA = chart_s[(size_t)(rkA * B_DIM + bA) * NCELLS + rcA];
            exval[it0] = psum[0][0] + psum[0][1] + psum[0][2] + psum[0][3] + lsA + rsA;
            if (it1v) {
                const float lsB = chart_s[(size_t)(lkB * B_DIM + bB) * NCELLS + lcB];
                const float rsB = chart_s[(size_t)(rkB * B_DIM + bB) * NCELLS + rcB];
                exval[it0 + 1] = psum[1][0] + psum[1][1] + psum[1][2] + psum[1][3] + lsB + rsB;
            }
        }
    }
}

// ---------------------------------------------------------------------------
// K3b: per flagged row, pick exact top-2 (z-ascending list + strict '>'
// replicates jax lowest-index tie-break), emit outputs + gather X.
// ---------------------------------------------------------------------------
__global__ __launch_bounds__(256)
void refine_pick(const float* __restrict__ chart_h,
                 const uint32_t* __restrict__ items,
                 const int* __restrict__ rowbase,
                 const int* __restrict__ flags,
                 const float* __restrict__ exval,
                 uint16_t* __restrict__ X,
                 float* __restrict__ out)
{
    const int row = blockIdx.x;
    const int nc = flags[row];
    if (nc == 0) return;
    const int b = row / L_DIM, pos = row % L_DIM;
    const int t = threadIdx.x;

    __shared__ int top_z[2];

    if (t == 0) {
        const int base = rowbase[row];
        float v1 = -3.4e38f; int c1 = -1;
        for (int c = 0; c < nc; ++c) {
            const float v = exval[base + c];
            if (v > v1) { v1 = v; c1 = c; }
        }
        float v2 = -3.4e38f; int c2 = -1;
        for (int c = 0; c < nc; ++c) {
            if (c == c1) continue;
            const float v = exval[base + c];
            if (v > v2) { v2 = v; c2 = c; }
        }
        const int i1 = (int)(items[base + c1] & 63u);
        const int i2 = (int)(items[base + c2] & 63u);
        top_z[0] = i1; top_z[1] = i2;
        emit_outputs(row, i1, i2, v1, v2, out);
    }
    __syncthreads();
    gather_x(row, pos, b, top_z, chart_h, X, t);
}

// ---------------------------------------------------------------------------
// transpose_wc: WcT[o][i] = bf16(Wc[i][o])
// ---------------------------------------------------------------------------
__global__ __launch_bounds__(256)
void transpose_wc(const float* __restrict__ Wc, uint16_t* __restrict__ WcT)
{
    __shared__ float tbuf[64][65];
    const int i0 = blockIdx.x * 64;
    const int o0 = blockIdx.y * 64;
    const int c = threadIdx.x & 63, r4 = threadIdx.x >> 6;
    for (int rr = r4; rr < 64; rr += 4)
        tbuf[rr][c] = Wc[(size_t)(i0 + rr) * 512 + o0 + c];
    __syncthreads();
    for (int rr = r4; rr < 64; rr += 4)
        WcT[(size_t)(o0 + rr) * 1024 + i0 + c] = f2bf(tbuf[c][rr]);
}

// ---------------------------------------------------------------------------
// K4: H = tanh(X @ WcT^T + bc)  (bf16 in, f32 out)
// ---------------------------------------------------------------------------
typedef __bf16 bf16x8 __attribute__((ext_vector_type(8)));

__global__ __launch_bounds__(256, 2)
void gemm_compose(const uint16_t* __restrict__ A,
                  const uint16_t* __restrict__ Bm,
                  const float* __restrict__ bias,
                  float* __restrict__ C,
                  int M, int Nn, int Kk)
{
    __shared__ uint16_t As[128 * 64];
    __shared__ uint16_t Bs[128 * 64];

    const int tid  = threadIdx.x;
    const int wave = tid >> 6, lane = tid & 63;
    const int m0 = blockIdx.x * 128, n0 = blockIdx.y * 128;
    const int wm = (wave & 1) * 64, wn = (wave >> 1) * 64;
    const int col_l = lane & 15, quad = lane >> 4;
    const int lrow = lane >> 3;
    const int lcol = (lane & 7) * 8;

    f32x4 acc[4][4];
#pragma unroll
    for (int i = 0; i < 4; ++i)
#pragma unroll
        for (int j = 0; j < 4; ++j) acc[i][j] = (f32x4){0.f, 0.f, 0.f, 0.f};

    for (int k0 = 0; k0 < Kk; k0 += 64) {
        __syncthreads();
#pragma unroll
        for (int i = 0; i < 4; ++i) {
            const int q = wave * 4 + i;
            const int r = q * 8 + lrow;
            GLD16(A  + (size_t)(m0 + r) * Kk + k0 + lcol, (char*)As + q * 1024);
            GLD16(Bm + (size_t)(n0 + r) * Kk + k0 + lcol, (char*)Bs + q * 1024);
        }
        __syncthreads();
#pragma unroll
        for (int kk = 0; kk < 64; kk += 32) {
            bf16x8 af[4], bfr[4];
#pragma unroll
            for (int mi = 0; mi < 4; ++mi)
                af[mi] = *(const bf16x8*)&As[(wm + mi * 16 + col_l) * 64 + kk + quad * 8];
#pragma unroll
            for (int ni = 0; ni < 4; ++ni)
                bfr[ni] = *(const bf16x8*)&Bs[(wn + ni * 16 + col_l) * 64 + kk + quad * 8];
#pragma unroll
            for (int mi = 0; mi < 4; ++mi)
#pragma unroll
                for (int ni = 0; ni < 4; ++ni)
                    acc[mi][ni] = __builtin_amdgcn_mfma_f32_16x16x32_bf16(
                        af[mi], bfr[ni], acc[mi][ni], 0, 0, 0);
        }
    }

#pragma unroll
    for (int ni = 0; ni < 4; ++ni) {
        const int ncol = n0 + wn + ni * 16 + col_l;
        const float bv = bias[ncol];
#pragma unroll
        for (int mi = 0; mi < 4; ++mi) {
            const int mrow = m0 + wm + mi * 16 + quad * 4;
#pragma unroll
            for (int r = 0; r < 4; ++r)
                C[(size_t)(mrow + r) * Nn + ncol] = tanhf(acc[mi][ni][r] + bv);
        }
    }
}

// ---------------------------------------------------------------------------
// K5: unit-normalize H rows -> topk_h
// ---------------------------------------------------------------------------
__global__ __launch_bounds__(256)
void norm_rows(const float* __restrict__ H, float* __restrict__ out)
{
    const int row = blockIdx.x;
    const float* h = H + (size_t)row * SZ;
    const int t = threadIdx.x;
    const int wave = t >> 6, lane = t & 63;
    const float a = h[t], c = h[t + 256];
    float ss = a * a + c * c;
#pragma unroll
    for (int o = 32; o > 0; o >>= 1) ss += __shfl_down(ss, o);
    __shared__ float wsum[4];
    if (lane == 0) wsum[wave] = ss;
    __syncthreads();
    const float inv = rsqrtf(wsum[0] + wsum[1] + wsum[2] + wsum[3]);
    out[(size_t)row * SZ + t]       = a * inv;
    out[(size_t)row * SZ + t + 256] = c * inv;
}

// ---------------------------------------------------------------------------
extern "C" void kernel_launch(void* const* d_in, const int* in_sizes, int n_in,
                              void* d_out, int out_size, void* d_ws, size_t ws_size,
                              hipStream_t stream)
{
    const float* chart_h = (const float*)d_in[0];
    const float* chart_s = (const float*)d_in[1];
    const float* mat = (const float*)d_in[4];
    const float* Wc  = (const float*)d_in[5];
    const float* bc  = (const float*)d_in[6];
    float* out = (float*)d_out;

    // workspace (peak 125,704,192 B; proven ws >= 125,829,120 in r2):
    //   CH16  f16 [57856][512] @ 0            (59,244,544)  alive P0->K2
    //   T16   f16 [57856][512] @ 59,244,544   (59,244,544)  alive K1->K2
    //   MAT16 f16 [512][512]   @ 118,489,088  (   524,288)  dead after K1:
    //     ITEMS u32[49152]     @ 118,489,088  (   196,608)  (overlays MAT16)
    //     EXVAL f32[49152]     @ 118,685,696  (   196,608)
    //   ROWBASE i32[1536]      @ 119,013,376  (     6,144)
    //   COUNTER i32            @ 119,019,520  (       256)
    //   FLAGS i32 [1536]       @ 119,406,592  (     6,144)
    //   X     bf16[3072][1024] @ 119,412,736  ( 6,291,456)  -> end 125,704,192
    //   WcT   bf16[512][1024]  @ 0            (reuses CH16 region after K2)
    //   H     f32 [3072][512]  @ 1,048,576    (reuses CH16 region after K2)
    char* ws = (char*)d_ws;
    _Float16* CH16  = (_Float16*)ws;
    _Float16* T16   = (_Float16*)(ws + 59244544);
    _Float16* MAT16 = (_Float16*)(ws + 118489088);
    uint32_t* ITEMS = (uint32_t*)(ws + 118489088);
    float*    EXVAL = (float*)(ws + 118685696);
    int*      RBASE = (int*)(ws + 119013376);
    int*      CNT   = (int*)(ws + 119019520);
    int*      FLAGS = (int*)(ws + 119406592);
    uint16_t* X     = (uint16_t*)(ws + 119412736);
    uint16_t* WcT   = (uint16_t*)ws;
    float*    H     = (float*)(ws + 1048576);

    hipMemsetAsync(CNT, 0, 4, stream);
    // P0: f16 conversions (x16 chart, x64 mat); 14464*2048 = 29,622,272 exact
    prep<<<dim3(14464), 256, 0, stream>>>(chart_h, mat, CH16, MAT16);
    // K1: T' = CH16 @ MAT16^T  (57856x512x512, single-pass f16 MFMA)
    gemm_f16<<<dim3(4, 452), 256, 0, stream>>>(CH16, MAT16, T16, 57856, 512, 512);
    // K2: cheap scores + top3 + candidate queue; outputs + X for clean rows
    score_topk<<<dim3(B_DIM * L_DIM), 256, 0, stream>>>(CH16, T16, chart_s, chart_h,
                                                        ITEMS, RBASE, CNT, FLAGS, X, out);
    // (CH16/T16/MAT16 dead from here; WcT/H overlap CH16, ITEMS overlays MAT16)
    transpose_wc<<<dim3(16, 8), 256, 0, stream>>>(Wc, WcT);
    // K3a: exact eval, block per item pair (mat shared within pair)
    refine_eval<<<dim3(1024), 256, 0, stream>>>(chart_h, chart_s, mat, ITEMS, CNT, EXVAL);
    // K3b: per-row exact top-2 + outputs + X
    refine_pick<<<dim3(B_DIM * L_DIM), 256, 0, stream>>>(chart_h, ITEMS, RBASE, FLAGS,
                                                         EXVAL, X, out);
    // K4: H = tanh(X @ WcT^T + bc)
    gemm_compose<<<dim3(24, 4), 256, 0, stream>>>(X, WcT, bc, H, 3072, 512, 1024);
    // K5: topk_h = H / ||H||
    norm_rows<<<dim3(3072), 256, 0, stream>>>(H, out);
}

// Round 7
// 321.600 us; speedup vs baseline: 1.5579x; 1.0076x over previous
//
#include <hip/hip_runtime.h>
#include <cstdint>
#include <cstddef>

// ---------------------------------------------------------------------------
// Problem constants (LEVEL=16, LENGTH=64, TOPK=2, SIZE=512, BATCH=32)
// Inputs f32, outputs f32. Uniform absmax threshold 2.06 across outputs =>
// precision only matters for ORDERING near-ties (topk_n_idx needs |dn|<=2).
// Cheap path: f16 MFMA scores, f16 error only on the T path (sigma ~0.011).
// Rows with cheap top-2/3 gaps < DELTA=0.25 get exact f32 refinement over the
// candidate set {z: cheap[z] >= cheap_top2 - DELTA}.
//
// r6 lesson: top-5 is the harness's 474MB ws-poison fill (72us, untouchable);
// all our kernels < 71us. Largest controllable block was prep(28us,179MB) +
// gemm_f16(~40us, A double-fetched: 4 n-tiles of an m-tile land on different
// XCDs). r7: fuse f32->f16 convert into the GEMM A-staging and use a full-
// width tile (64m x 512n, grid 904) so chart_h is fetched exactly once.
// ---------------------------------------------------------------------------
#define B_DIM   32
#define L_DIM   48
#define NCELLS  904
#define SZ      512
#define NEGF    (-1e8f)
#define DELTA   0.25f
#define MAXC    32          // max candidates per row kept (z-ascending)

// d_out layout (f32), outputs concatenated flat in return order
#define OFF_S   1572864
#define OFF_N   1575936
#define OFF_L   1579008
#define OFF_R   1582080

typedef _Float16  f16x8 __attribute__((ext_vector_type(8)));
typedef float     f32x4 __attribute__((ext_vector_type(4)));

static __device__ __forceinline__ uint16_t f2bf(float f) {
    uint32_t u = __builtin_bit_cast(uint32_t, f);
    u += 0x7fffu + ((u >> 16) & 1u);
    return (uint16_t)(u >> 16);
}

#define GLD16(gp, lp) __builtin_amdgcn_global_load_lds(                        \
        (__attribute__((address_space(1))) void*)(gp),                         \
        (__attribute__((address_space(3))) void*)(lp), 16, 0, 0)

static __device__ __forceinline__ int level_off(int n) {
    return n * 64 - (n * (n - 1)) / 2;
}

// ---------------------------------------------------------------------------
// P0: matf16 = f16(64*mat)  (tiny: 1MB read)
// ---------------------------------------------------------------------------
__global__ __launch_bounds__(256)
void prep_mat(const float* __restrict__ mat, _Float16* __restrict__ mat16)
{
    const size_t j = ((size_t)blockIdx.x * 256 + threadIdx.x) * 8;
    const float4 c = *(const float4*)(mat + j);
    const float4 d = *(const float4*)(mat + j + 4);
    f16x8 w;
    w[0]=(_Float16)(c.x*64.f); w[1]=(_Float16)(c.y*64.f);
    w[2]=(_Float16)(c.z*64.f); w[3]=(_Float16)(c.w*64.f);
    w[4]=(_Float16)(d.x*64.f); w[5]=(_Float16)(d.y*64.f);
    w[6]=(_Float16)(d.z*64.f); w[7]=(_Float16)(d.w*64.f);
    *(f16x8*)(mat16 + j) = w;
}

// ---------------------------------------------------------------------------
// K1: T'[m,e] = sum_d f16(16*A[m,d]) * B16[e,d]   (A f32 in HBM; convert in
// registers after f32 LDS staging). Tile 64m x 512n (full N) -> A fetched
// exactly once. BK=32. 4 waves: wave w owns n-range [128w,128w+128).
// T' is 1024x the true value; consumers divide.
// ---------------------------------------------------------------------------
__global__ __launch_bounds__(256, 2)
void gemm_fused(const float* __restrict__ A,        // chart_h f32 [57856][512]
                const _Float16* __restrict__ Bm,    // mat16 [512][512]
                _Float16* __restrict__ C)           // T16 [57856][512]
{
    __shared__ float    As[64 * 32];     //  8 KB (f32 tile)
    __shared__ _Float16 Bs[512 * 32];    // 32 KB

    const int t = threadIdx.x;
    const int wave = t >> 6, lane = t & 63;
    const int m0 = blockIdx.x * 64;
    const int col_l = lane & 15, quad = lane >> 4;

    f32x4 acc[4][8];
#pragma unroll
    for (int i = 0; i < 4; ++i)
#pragma unroll
        for (int j = 0; j < 8; ++j) acc[i][j] = (f32x4){0.f, 0.f, 0.f, 0.f};

    for (int k0 = 0; k0 < 512; k0 += 32) {
        __syncthreads();
        // A: 8 chunks of 1KB (8 rows x 32 f32 each); 2 per wave
#pragma unroll
        for (int i = 0; i < 2; ++i) {
            const int q = wave * 2 + i;
            GLD16(A + (size_t)(m0 + q * 8 + (lane >> 3)) * 512 + k0 + (lane & 7) * 4,
                  (char*)As + q * 1024);
        }
        // B: 32 chunks of 1KB (16 rows x 32 f16 each); 8 per wave
#pragma unroll
        for (int i = 0; i < 8; ++i) {
            const int q = wave * 8 + i;
            GLD16(Bm + (size_t)(q * 16 + (lane >> 2)) * 512 + k0 + (lane & 3) * 8,
                  (char*)Bs + q * 1024);
        }
        __syncthreads();

        f16x8 af[4];
#pragma unroll
        for (int mi = 0; mi < 4; ++mi) {
            const float* ap = &As[(mi * 16 + col_l) * 32 + quad * 8];
            const f32x4 p0 = *(const f32x4*)ap;
            const f32x4 p1 = *(const f32x4*)(ap + 4);
#pragma unroll
            for (int j = 0; j < 4; ++j) {
                af[mi][j]     = (_Float16)(p0[j] * 16.f);
                af[mi][j + 4] = (_Float16)(p1[j] * 16.f);
            }
        }
#pragma unroll
        for (int ni = 0; ni < 8; ++ni) {
            const f16x8 bf = *(const f16x8*)&Bs[(wave * 128 + ni * 16 + col_l) * 32 + quad * 8];
#pragma unroll
            for (int mi = 0; mi < 4; ++mi)
                acc[mi][ni] = __builtin_amdgcn_mfma_f32_16x16x32_f16(
                    af[mi], bf, acc[mi][ni], 0, 0, 0);
        }
    }

    // epilogue: C/D layout col=lane&15, row=quad*4+reg
#pragma unroll
    for (int ni = 0; ni < 8; ++ni) {
        const int ncol = wave * 128 + ni * 16 + col_l;
#pragma unroll
        for (int mi = 0; mi < 4; ++mi) {
            const int mrow = m0 + mi * 16 + quad * 4;
#pragma unroll
            for (int r = 0; r < 4; ++r)
                C[(size_t)(mrow + r) * 512 + ncol] = (_Float16)acc[mi][ni][r];
        }
    }
}

// ---------------------------------------------------------------------------
// shared epilogue helpers
// ---------------------------------------------------------------------------
static __device__ __forceinline__ void emit_outputs(
    int row, int i1, int i2, float v1, float v2, float* out)
{
    out[OFF_S + row * 2 + 0] = v1;
    out[OFF_S + row * 2 + 1] = v2;
    out[OFF_N + row * 2 + 0] = (float)(i1 >> 2);
    out[OFF_N + row * 2 + 1] = (float)(i2 >> 2);
    out[OFF_L + row * 2 + 0] = (float)((i1 >> 1) & 1);
    out[OFF_L + row * 2 + 1] = (float)((i2 >> 1) & 1);
    out[OFF_R + row * 2 + 0] = (float)(i1 & 1);
    out[OFF_R + row * 2 + 1] = (float)(i2 & 1);
}

static __device__ __forceinline__ void gather_x(
    int row, int pos, int b, const int* top_z,
    const float* __restrict__ chart_h, uint16_t* __restrict__ X, int tid)
{
#pragma unroll
    for (int kq = 0; kq < 2; ++kq) {
        const int z = top_z[kq];
        const int n = z >> 2, lk = (z >> 1) & 1, rk = z & 1;
        const int lcell = level_off(n) + pos;
        const int rcell = level_off(15 - n) + pos + n + 1;
        const float* srcl = chart_h + ((size_t)(lk * B_DIM + b) * NCELLS + lcell) * SZ;
        const float* srcr = chart_h + ((size_t)(rk * B_DIM + b) * NCELLS + rcell) * SZ;
        uint16_t* dst = X + ((size_t)row * 2 + kq) * 1024;
        const int e = tid * 2;
        const float2 a = *(const float2*)(srcl + e);
        const float2 c = *(const float2*)(srcr + e);
        *(uint32_t*)(dst + e)       = (uint32_t)f2bf(a.x) | ((uint32_t)f2bf(a.y) << 16);
        *(uint32_t*)(dst + 512 + e) = (uint32_t)f2bf(c.x) | ((uint32_t)f2bf(c.y) << 16);
    }
}

// ---------------------------------------------------------------------------
// K2: cheap scores (lh f32 x T16 f16), top-3, near-tie flagging + candidate
// queue (ballot compaction). Clean rows emit outputs + gather X here.
// ---------------------------------------------------------------------------
__global__ __launch_bounds__(256)
void score_topk(const float* __restrict__ chart_h,   // f32
                const _Float16* __restrict__ T16,    // x1024
                const float* __restrict__ chart_s,
                uint32_t* __restrict__ items,        // queue entries (row<<6|z)
                int* __restrict__ rowbase,           // [1536]
                int* __restrict__ counter,           // 1 int, pre-zeroed
                int* __restrict__ flags,             // [1536]: nc (0 = clean)
                uint16_t* __restrict__ X,
                float* __restrict__ out)
{
    const int b   = blockIdx.x / L_DIM;
    const int pos = blockIdx.x % L_DIM;
    const int row = blockIdx.x;
    const int wave = threadIdx.x >> 6, lane = threadIdx.x & 63;

    __shared__ float s_sh[64];
    __shared__ int top_z[2];
    __shared__ int flag_sh;

#pragma unroll
    for (int ni = 0; ni < 4; ++ni) {
        const int n = wave * 4 + ni;
        const int lcell = level_off(n) + pos;
        const int rcell = level_off(15 - n) + pos + n + 1;

        const float* lp0 = chart_h + ((size_t)(0 * B_DIM + b) * NCELLS + lcell) * SZ + lane * 8;
        const float* lp1 = chart_h + ((size_t)(1 * B_DIM + b) * NCELLS + lcell) * SZ + lane * 8;
        const float4 l0a = *(const float4*)lp0, l0b = *(const float4*)(lp0 + 4);
        const float4 l1a = *(const float4*)lp1, l1b = *(const float4*)(lp1 + 4);
        const f16x8 t0 = *(const f16x8*)(T16 + ((size_t)(0 * B_DIM + b) * NCELLS + rcell) * SZ + lane * 8);
        const f16x8 t1 = *(const f16x8*)(T16 + ((size_t)(1 * B_DIM + b) * NCELLS + rcell) * SZ + lane * 8);

        float l0[8] = {l0a.x, l0a.y, l0a.z, l0a.w, l0b.x, l0b.y, l0b.z, l0b.w};
        float l1[8] = {l1a.x, l1a.y, l1a.z, l1a.w, l1b.x, l1b.y, l1b.z, l1b.w};

        float d00 = 0.f, d01 = 0.f, d10 = 0.f, d11 = 0.f;
#pragma unroll
        for (int j = 0; j < 8; ++j) {
            const float c0 = (float)t0[j], c1 = (float)t1[j];
            d00 += l0[j] * c0; d01 += l0[j] * c1;
            d10 += l1[j] * c0; d11 += l1[j] * c1;
        }
#pragma unroll
        for (int o = 32; o > 0; o >>= 1) {
            d00 += __shfl_down(d00, o);
            d01 += __shfl_down(d01, o);
            d10 += __shfl_down(d10, o);
            d11 += __shfl_down(d11, o);
        }
        if (lane == 0) {
            const float ls0 = chart_s[(size_t)(0 * B_DIM + b) * NCELLS + lcell];
            const float ls1 = chart_s[(size_t)(1 * B_DIM + b) * NCELLS + lcell];
            const float rs0 = chart_s[(size_t)(0 * B_DIM + b) * NCELLS + rcell];
            const float rs1 = chart_s[(size_t)(1 * B_DIM + b) * NCELLS + rcell];
            const float inv = 1.0f / 1024.0f;        // undo x1024 on T'
            s_sh[n * 4 + 0] = d00 * inv + ls0 + rs0;
            s_sh[n * 4 + 1] = d01 * inv + ls0 + rs1;
            s_sh[n * 4 + 2] = d10 * inv + ls1 + rs0;
            s_sh[n * 4 + 3] = d11 * inv + ls1 + rs1;
        }
    }
    __syncthreads();

    if (threadIdx.x < 64) {
        float v = s_sh[lane];
        if (lane == 2 || lane == 3) v = NEGF;        // penalty mask
        float v1 = v; int i1 = lane;
#pragma unroll
        for (int o = 32; o > 0; o >>= 1) {
            float ov = __shfl_down(v1, o);
            int   oi = __shfl_down(i1, o);
            if (ov > v1 || (ov == v1 && oi < i1)) { v1 = ov; i1 = oi; }
        }
        v1 = __shfl(v1, 0); i1 = __shfl(i1, 0);
        float v2 = (lane == i1) ? -3.4e38f : v; int i2 = lane;
#pragma unroll
        for (int o = 32; o > 0; o >>= 1) {
            float ov = __shfl_down(v2, o);
            int   oi = __shfl_down(i2, o);
            if (ov > v2 || (ov == v2 && oi < i2)) { v2 = ov; i2 = oi; }
        }
        v2 = __shfl(v2, 0); i2 = __shfl(i2, 0);
        float v3 = (lane == i1 || lane == i2) ? -3.4e38f : v;
#pragma unroll
        for (int o = 32; o > 0; o >>= 1) {
            const float ov = __shfl_down(v3, o);
            if (ov > v3) v3 = ov;
        }
        v3 = __shfl(v3, 0);

        const int f = (v1 - v2 < DELTA) || (v2 - v3 < DELTA);
        const bool cand = (v >= v2 - DELTA);
        const unsigned long long mask = __ballot(cand);
        const int nc_full = __popcll(mask);
        const int nc = nc_full < MAXC ? nc_full : MAXC;
        int base = 0;
        if (lane == 0) {
            flags[row] = f ? nc : 0;
            flag_sh = f;
            if (f) base = atomicAdd(counter, nc);
            rowbase[row] = base;
            top_z[0] = i1; top_z[1] = i2;
            if (!f) emit_outputs(row, i1, i2, v1, v2, out);
        }
        base = __shfl(base, 0);
        if (f && cand) {
            const int rank = __popcll(mask & ((1ull << lane) - 1ull));
            if (rank < MAXC) items[base + rank] = ((uint32_t)row << 6) | (uint32_t)lane;
        }
    }
    __syncthreads();

    if (!flag_sh)
        gather_x(row, pos, b, top_z, chart_h, X, threadIdx.x);
}

// ---------------------------------------------------------------------------
// K3a: exact f32 eval, block per ITEM PAIR (both items share the 1MB mat
// sweep). Waves split the e-range; lane owns rh[8*lane..+8) in regs.
// ---------------------------------------------------------------------------
__global__ __launch_bounds__(256)
void refine_eval(const float* __restrict__ chart_h,
                 const float* __restrict__ chart_s,
                 const float* __restrict__ mat,
                 const uint32_t* __restrict__ items,
                 const int* __restrict__ counter,
                 float* __restrict__ exval)
{
    const int total = *counter;
    const int t = threadIdx.x;
    const int wave = t >> 6, lane = t & 63;

    __shared__ float lh_sh[2][512];
    __shared__ float psum[2][4];

    for (int p = blockIdx.x; 2 * p < total; p += gridDim.x) {
        const int it0 = 2 * p;
        const int it1v = (2 * p + 1 < total);
        const uint32_t item0 = items[it0];
        const uint32_t item1 = it1v ? items[it0 + 1] : item0;

        int rowA = item0 >> 6, zA = item0 & 63;
        int bA = rowA / L_DIM, posA = rowA % L_DIM;
        int nA = zA >> 2, lkA = (zA >> 1) & 1, rkA = zA & 1;
        int lcA = level_off(nA) + posA, rcA = level_off(15 - nA) + posA + nA + 1;
        int rowB = item1 >> 6, zB = item1 & 63;
        int bB = rowB / L_DIM, posB = rowB % L_DIM;
        int nB = zB >> 2, lkB = (zB >> 1) & 1, rkB = zB & 1;
        int lcB = level_off(nB) + posB, rcB = level_off(15 - nB) + posB + nB + 1;

        const float* lhA = chart_h + ((size_t)(lkA * B_DIM + bA) * NCELLS + lcA) * SZ;
        const float* rhA = chart_h + ((size_t)(rkA * B_DIM + bA) * NCELLS + rcA) * SZ;
        const float* lhB = chart_h + ((size_t)(lkB * B_DIM + bB) * NCELLS + lcB) * SZ;
        const float* rhB = chart_h + ((size_t)(rkB * B_DIM + bB) * NCELLS + rcB) * SZ;

        __syncthreads();
        lh_sh[0][t] = lhA[t]; lh_sh[0][t + 256] = lhA[t + 256];
        lh_sh[1][t] = lhB[t]; lh_sh[1][t + 256] = lhB[t + 256];
        const float4 rA0 = *(const float4*)(rhA + lane * 8);
        const float4 rA1 = *(const float4*)(rhA + lane * 8 + 4);
        const float4 rB0 = *(const float4*)(rhB + lane * 8);
        const float4 rB1 = *(const float4*)(rhB + lane * 8 + 4);
        __syncthreads();

        const float* mb = mat + (size_t)(wave * 128) * 512 + lane * 8;
        float a00 = 0.f, a01 = 0.f, b00 = 0.f, b01 = 0.f;
        for (int e = 0; e < 128; e += 2) {
            const float4 m0 = *(const float4*)(mb + (size_t)(e + 0) * 512);
            const float4 m1 = *(const float4*)(mb + (size_t)(e + 0) * 512 + 4);
            const float4 m2 = *(const float4*)(mb + (size_t)(e + 1) * 512);
            const float4 m3 = *(const float4*)(mb + (size_t)(e + 1) * 512 + 4);
            const int eg = wave * 128 + e;
            const float lA0 = lh_sh[0][eg],     lB0 = lh_sh[1][eg];
            const float lA1 = lh_sh[0][eg + 1], lB1 = lh_sh[1][eg + 1];
            const float dA0 = m0.x*rA0.x + m0.y*rA0.y + m0.z*rA0.z + m0.w*rA0.w
                            + m1.x*rA1.x + m1.y*rA1.y + m1.z*rA1.z + m1.w*rA1.w;
            const float dB0 = m0.x*rB0.x + m0.y*rB0.y + m0.z*rB0.z + m0.w*rB0.w
                            + m1.x*rB1.x + m1.y*rB1.y + m1.z*rB1.z + m1.w*rB1.w;
            const float dA1 = m2.x*rA0.x + m2.y*rA0.y + m2.z*rA0.z + m2.w*rA0.w
                            + m3.x*rA1.x + m3.y*rA1.y + m3.z*rA1.z + m3.w*rA1.w;
            const float dB1 = m2.x*rB0.x + m2.y*rB0.y + m2.z*rB0.z + m2.w*rB0.w
                            + m3.x*rB1.x + m3.y*rB1.y + m3.z*rB1.z + m3.w*rB1.w;
            a00 += lA0 * dA0; a01 += lA1 * dA1;
            b00 += lB0 * dB0; b01 += lB1 * dB1;
        }
        float sA = a00 + a01, sB = b00 + b01;
#pragma unroll
        for (int o = 32; o > 0; o >>= 1) {
            sA += __shfl_down(sA, o);
            sB += __shfl_down(sB, o);
        }
        if (lane == 0) { psum[0][wave] = sA; psum[1][wave] = sB; }
        __syncthreads();
        if (t == 0) {
            const float lsA = chart_s[(size_t)(lkA * B_DIM + bA) * NCELLS + lcA];
            const float rsA = chart_s[(size_t)(rkA * B_DIM + bA) * NCELLS + rcA];
            exval[it0] = psum[0][0] + psum[0][1] + psum[0][2] + psum[0][3] + lsA + rsA;
            if (it1v) {
                const float lsB = chart_s[(size_t)(lkB * B_DIM + bB) * NCELLS + lcB];
                const float rsB = chart_s[(size_t)(rkB * B_DIM + bB) * NCELLS + rcB];
                exval[it0 + 1] = psum[1][0] + psum[1][1] + psum[1][2] + psum[1][3] + lsB + rsB;
            }
        }
    }
}

// ---------------------------------------------------------------------------
// K3b: per flagged row, pick exact top-2 (z-ascending list + strict '>'
// replicates jax lowest-index tie-break), emit outputs + gather X.
// ---------------------------------------------------------------------------
__global__ __launch_bounds__(256)
void refine_pick(const float* __restrict__ chart_h,
                 const uint32_t* __restrict__ items,
                 const int* __restrict__ rowbase,
                 const int* __restrict__ flags,
                 const float* __restrict__ exval,
                 uint16_t* __restrict__ X,
                 float* __restrict__ out)
{
    const int row = blockIdx.x;
    const int nc = flags[row];
    if (nc == 0) return;
    const int b = row / L_DIM, pos = row % L_DIM;
    const int t = threadIdx.x;

    __shared__ int top_z[2];

    if (t == 0) {
        const int base = rowbase[row];
        float v1 = -3.4e38f; int c1 = -1;
        for (int c = 0; c < nc; ++c) {
            const float v = exval[base + c];
            if (v > v1) { v1 = v; c1 = c; }
        }
        float v2 = -3.4e38f; int c2 = -1;
        for (int c = 0; c < nc; ++c) {
            if (c == c1) continue;
            const float v = exval[base + c];
            if (v > v2) { v2 = v; c2 = c; }
        }
        const int i1 = (int)(items[base + c1] & 63u);
        const int i2 = (int)(items[base + c2] & 63u);
        top_z[0] = i1; top_z[1] = i2;
        emit_outputs(row, i1, i2, v1, v2, out);
    }
    __syncthreads();
    gather_x(row, pos, b, top_z, chart_h, X, t);
}

// ---------------------------------------------------------------------------
// transpose_wc: WcT[o][i] = bf16(Wc[i][o])
// ---------------------------------------------------------------------------
__global__ __launch_bounds__(256)
void transpose_wc(const float* __restrict__ Wc, uint16_t* __restrict__ WcT)
{
    __shared__ float tbuf[64][65];
    const int i0 = blockIdx.x * 64;
    const int o0 = blockIdx.y * 64;
    const int c = threadIdx.x & 63, r4 = threadIdx.x >> 6;
    for (int rr = r4; rr < 64; rr += 4)
        tbuf[rr][c] = Wc[(size_t)(i0 + rr) * 512 + o0 + c];
    __syncthreads();
    for (int rr = r4; rr < 64; rr += 4)
        WcT[(size_t)(o0 + rr) * 1024 + i0 + c] = f2bf(tbuf[c][rr]);
}

// ---------------------------------------------------------------------------
// K4: H = tanh(X @ WcT^T + bc)  (bf16 in, f32 out)
// ---------------------------------------------------------------------------
typedef __bf16 bf16x8 __attribute__((ext_vector_type(8)));

__global__ __launch_bounds__(256, 2)
void gemm_compose(const uint16_t* __restrict__ A,
                  const uint16_t* __restrict__ Bm,
                  const float* __restrict__ bias,
                  float* __restrict__ C,
                  int M, int Nn, int Kk)
{
    __shared__ uint16_t As[128 * 64];
    __shared__ uint16_t Bs[128 * 64];

    const int tid  = threadIdx.x;
    const int wave = tid >> 6, lane = tid & 63;
    const int m0 = blockIdx.x * 128, n0 = blockIdx.y * 128;
    const int wm = (wave & 1) * 64, wn = (wave >> 1) * 64;
    const int col_l = lane & 15, quad = lane >> 4;
    const int lrow = lane >> 3;
    const int lcol = (lane & 7) * 8;

    f32x4 acc[4][4];
#pragma unroll
    for (int i = 0; i < 4; ++i)
#pragma unroll
        for (int j = 0; j < 4; ++j) acc[i][j] = (f32x4){0.f, 0.f, 0.f, 0.f};

    for (int k0 = 0; k0 < Kk; k0 += 64) {
        __syncthreads();
#pragma unroll
        for (int i = 0; i < 4; ++i) {
            const int q = wave * 4 + i;
            const int r = q * 8 + lrow;
            GLD16(A  + (size_t)(m0 + r) * Kk + k0 + lcol, (char*)As + q * 1024);
            GLD16(Bm + (size_t)(n0 + r) * Kk + k0 + lcol, (char*)Bs + q * 1024);
        }
        __syncthreads();
#pragma unroll
        for (int kk = 0; kk < 64; kk += 32) {
            bf16x8 af[4], bfr[4];
#pragma unroll
            for (int mi = 0; mi < 4; ++mi)
                af[mi] = *(const bf16x8*)&As[(wm + mi * 16 + col_l) * 64 + kk + quad * 8];
#pragma unroll
            for (int ni = 0; ni < 4; ++ni)
                bfr[ni] = *(const bf16x8*)&Bs[(wn + ni * 16 + col_l) * 64 + kk + quad * 8];
#pragma unroll
            for (int mi = 0; mi < 4; ++mi)
#pragma unroll
                for (int ni = 0; ni < 4; ++ni)
                    acc[mi][ni] = __builtin_amdgcn_mfma_f32_16x16x32_bf16(
                        af[mi], bfr[ni], acc[mi][ni], 0, 0, 0);
        }
    }

#pragma unroll
    for (int ni = 0; ni < 4; ++ni) {
        const int ncol = n0 + wn + ni * 16 + col_l;
        const float bv = bias[ncol];
#pragma unroll
        for (int mi = 0; mi < 4; ++mi) {
            const int mrow = m0 + wm + mi * 16 + quad * 4;
#pragma unroll
            for (int r = 0; r < 4; ++r)
                C[(size_t)(mrow + r) * Nn + ncol] = tanhf(acc[mi][ni][r] + bv);
        }
    }
}

// ---------------------------------------------------------------------------
// K5: unit-normalize H rows -> topk_h
// ---------------------------------------------------------------------------
__global__ __launch_bounds__(256)
void norm_rows(const float* __restrict__ H, float* __restrict__ out)
{
    const int row = blockIdx.x;
    const float* h = H + (size_t)row * SZ;
    const int t = threadIdx.x;
    const int wave = t >> 6, lane = t & 63;
    const float a = h[t], c = h[t + 256];
    float ss = a * a + c * c;
#pragma unroll
    for (int o = 32; o > 0; o >>= 1) ss += __shfl_down(ss, o);
    __shared__ float wsum[4];
    if (lane == 0) wsum[wave] = ss;
    __syncthreads();
    const float inv = rsqrtf(wsum[0] + wsum[1] + wsum[2] + wsum[3]);
    out[(size_t)row * SZ + t]       = a * inv;
    out[(size_t)row * SZ + t + 256] = c * inv;
}

// ---------------------------------------------------------------------------
extern "C" void kernel_launch(void* const* d_in, const int* in_sizes, int n_in,
                              void* d_out, int out_size, void* d_ws, size_t ws_size,
                              hipStream_t stream)
{
    const float* chart_h = (const float*)d_in[0];
    const float* chart_s = (const float*)d_in[1];
    const float* mat = (const float*)d_in[4];
    const float* Wc  = (const float*)d_in[5];
    const float* bc  = (const float*)d_in[6];
    float* out = (float*)d_out;

    // workspace (peak ~66.5 MB; proven ws >= 125.8 MB):
    //   T16   f16 [57856][512] @ 0            (59,244,544)  alive K1->K2
    //   MAT16 f16 [512][512]   @ 59,244,544   (   524,288)  dead after K1
    //   ITEMS u32[49152]       @ 59,768,832   (   196,608)
    //   EXVAL f32[49152]       @ 59,965,440   (   196,608)
    //   RBASE i32[1536]        @ 60,162,048   (     6,144)
    //   CNT   i32              @ 60,168,192   (       256)
    //   FLAGS i32[1536]        @ 60,168,448   (     6,144)
    //   X     bf16[3072][1024] @ 60,174,592   ( 6,291,456)
    //   WcT   bf16[512][1024]  @ 0            (reuses T16 region after K2)
    //   H     f32 [3072][512]  @ 1,048,576    (reuses T16 region after K2)
    char* ws = (char*)d_ws;
    _Float16* T16   = (_Float16*)ws;
    _Float16* MAT16 = (_Float16*)(ws + 59244544);
    uint32_t* ITEMS = (uint32_t*)(ws + 59768832);
    float*    EXVAL = (float*)(ws + 59965440);
    int*      RBASE = (int*)(ws + 60162048);
    int*      CNT   = (int*)(ws + 60168192);
    int*      FLAGS = (int*)(ws + 60168448);
    uint16_t* X     = (uint16_t*)(ws + 60174592);
    uint16_t* WcT   = (uint16_t*)ws;
    float*    H     = (float*)(ws + 1048576);

    hipMemsetAsync(CNT, 0, 4, stream);
    // P0: mat16 = f16(64*mat)  (128*2048 = 262,144 exact)
    prep_mat<<<dim3(128), 256, 0, stream>>>(mat, MAT16);
    // K1: T' = f16(16*chart_h) @ MAT16^T, fused convert, full-N tile, A once
    gemm_fused<<<dim3(904), 256, 0, stream>>>(chart_h, MAT16, T16);
    // K2: cheap scores + top3 + candidate queue; outputs + X for clean rows
    score_topk<<<dim3(B_DIM * L_DIM), 256, 0, stream>>>(chart_h, T16, chart_s,
                                                        ITEMS, RBASE, CNT, FLAGS, X, out);
    // (T16/MAT16 dead from here; WcT/H overlay T16 region)
    transpose_wc<<<dim3(16, 8), 256, 0, stream>>>(Wc, WcT);
    // K3a: exact eval, block per item pair (mat shared within pair)
    refine_eval<<<dim3(1024), 256, 0, stream>>>(chart_h, chart_s, mat, ITEMS, CNT, EXVAL);
    // K3b: per-row exact top-2 + outputs + X
    refine_pick<<<dim3(B_DIM * L_DIM), 256, 0, stream>>>(chart_h, ITEMS, RBASE, FLAGS,
                                                         EXVAL, X, out);
    // K4: H = tanh(X @ WcT^T + bc)
    gemm_compose<<<dim3(24, 4), 256, 0, stream>>>(X, WcT, bc, H, 3072, 512, 1024);
    // K5: topk_h = H / ||H||
    norm_rows<<<dim3(3072), 256, 0, stream>>>(H, out);
}